// Round 12
// baseline (366.397 us; speedup 1.0000x reference)
//
#include <hip/hip_runtime.h>
#include <hip/hip_bf16.h>
#include <math.h>

// Problem constants (MultiQueryAttention: B=2, S=2048, D=1024, H=16, hd=64)
#define BB 2
#define SS 2048
#define DD 1024
#define NH 16
#define HD 64
#define MM (BB * SS)  // 4096 tokens

#define BK 32            // GEMM k-step

typedef __hip_bfloat16 bf16;
typedef __bf16 bf16_t;
typedef __attribute__((ext_vector_type(8))) __bf16 bf16x8;
typedef __attribute__((ext_vector_type(4))) __bf16 bf16x4;
typedef __attribute__((ext_vector_type(4))) float floatx4;

// (1/sqrt(64)) * log2(e): folded into Q at projection time so QK^T scores
// come out directly in the exp2 domain.
#define SCALEQ 0.18033688011112042f

// ---------------- runtime dtype detection (parallel) ----------------
// flag[0]==1 -> external tensors are fp32; flag[0]==0 -> bf16.
// flag[1] is always 0 (a "bf16" flag for the converted-input path).
__global__ void detect_dtype(const unsigned int* __restrict__ x, int* __restrict__ flag) {
    const int tid = threadIdx.x;  // 64 lanes
    int good = 0;
    for (int i = tid; i < 256; i += 64) {
        unsigned int bits = (x[i] & 0xFFFFu) << 16;
        float v = __uint_as_float(bits);
        float av = fabsf(v);
        if (av == 0.f || (av >= 9.5367431640625e-7f && av <= 64.f)) good++;
    }
#pragma unroll
    for (int s = 1; s < 64; s <<= 1) good += __shfl_xor(good, s);
    if (tid == 0) { flag[0] = (good >= 240) ? 0 : 1; flag[1] = 0; }
}

// ---------------- bulk fp32->bf16 conversion (or bf16 passthrough) -------
__device__ __forceinline__ void conv_seg(const void* __restrict__ in,
                                         bf16_t* __restrict__ out,
                                         int n, int f, int tid, int T) {
    if (f) {
        const float* p = (const float*)in;
        for (int i = tid * 8; i < n; i += T * 8) {
            float4 a = *(const float4*)(p + i);
            float4 b = *(const float4*)(p + i + 4);
            bf16x8 o;
            o[0] = (bf16_t)a.x; o[1] = (bf16_t)a.y; o[2] = (bf16_t)a.z; o[3] = (bf16_t)a.w;
            o[4] = (bf16_t)b.x; o[5] = (bf16_t)b.y; o[6] = (bf16_t)b.z; o[7] = (bf16_t)b.w;
            *(bf16x8*)(out + i) = o;
        }
    } else {
        const bf16_t* p = (const bf16_t*)in;
        for (int i = tid * 8; i < n; i += T * 8)
            *(bf16x8*)(out + i) = *(const bf16x8*)(p + i);
    }
}

__global__ __launch_bounds__(256) void conv_all(const void* __restrict__ x,
                                                const void* __restrict__ wq,
                                                const void* __restrict__ wk,
                                                const void* __restrict__ wv,
                                                const void* __restrict__ wo,
                                                bf16_t* __restrict__ xb,
                                                bf16_t* __restrict__ wqb,
                                                bf16_t* __restrict__ wkb,
                                                bf16_t* __restrict__ wvb,
                                                bf16_t* __restrict__ wob,
                                                const int* __restrict__ flag) {
    const int f = *flag;
    const int tid = blockIdx.x * blockDim.x + threadIdx.x;
    const int T = gridDim.x * blockDim.x;
    conv_seg(x, xb, MM * DD, f, tid, T);
    conv_seg(wq, wqb, DD * DD, f, tid, T);
    conv_seg(wk, wkb, HD * DD, f, tid, T);
    conv_seg(wv, wvb, HD * DD, f, tid, T);
    conv_seg(wo, wob, DD * DD, f, tid, T);
}

// ------- 64x64-tile bf16 projection GEMMs (256 thr, depth-2 prefetch) ----
// 4 waves in 2x2, 32x32/wave, acc[2][2]. KP=40 padded LDS (conflict-free),
// depth-2 NAMED register prefetch. 1152/1024 blocks.
#define KP 40

__global__ __launch_bounds__(256) void proj_qkv_b(const bf16_t* __restrict__ X,
                                                  const bf16_t* __restrict__ Wq,
                                                  const bf16_t* __restrict__ Wk,
                                                  const bf16_t* __restrict__ Wv,
                                                  bf16_t* __restrict__ QA,
                                                  bf16_t* __restrict__ Kp,
                                                  bf16_t* __restrict__ VpT) {
    __shared__ bf16_t As[64 * KP];
    __shared__ bf16_t Bs[64 * KP];

    const int tid = threadIdx.x;
    const int wave = tid >> 6, lane = tid & 63;
    const int lo = lane & 15, quad = lane >> 4;
    const int wr = wave >> 1, wc = wave & 1;       // 2x2 wave grid
    const int rowBase = blockIdx.x * 64;           // row tile (fastest dim)
    const int cb = blockIdx.y;                     // 0..17 (16=K, 17=V)

    const int rS = tid >> 2;
    const int c8 = (tid & 3) * 8;

    const bf16_t* arow = X + (size_t)(rowBase + rS) * DD + c8;
    const bf16_t* wrow;
    if (cb < 16)       wrow = Wq + (size_t)(cb * 64 + rS) * DD + c8;
    else if (cb == 16) wrow = Wk + (size_t)rS * DD + c8;
    else               wrow = Wv + (size_t)rS * DD + c8;

    floatx4 acc[2][2];
#pragma unroll
    for (int i = 0; i < 2; i++)
#pragma unroll
        for (int j = 0; j < 2; j++) acc[i][j] = (floatx4){0.f, 0.f, 0.f, 0.f};

    bf16x8 aR0 = *(const bf16x8*)(arow);
    bf16x8 bR0 = *(const bf16x8*)(wrow);
    bf16x8 aR1 = *(const bf16x8*)(arow + BK);
    bf16x8 bR1 = *(const bf16x8*)(wrow + BK);

    for (int k0 = 0; k0 < DD; k0 += 2 * BK) {
        __syncthreads();
        *(bf16x8*)&As[rS * KP + c8] = aR0;
        *(bf16x8*)&Bs[rS * KP + c8] = bR0;
        __syncthreads();
        if (k0 + 2 * BK < DD) {
            aR0 = *(const bf16x8*)(arow + k0 + 2 * BK);
            bR0 = *(const bf16x8*)(wrow + k0 + 2 * BK);
        }
        {
            bf16x8 afr[2], bfr[2];
#pragma unroll
            for (int i = 0; i < 2; i++)
                afr[i] = *(const bf16x8*)&As[(wr * 32 + i * 16 + lo) * KP + quad * 8];
#pragma unroll
            for (int j = 0; j < 2; j++)
                bfr[j] = *(const bf16x8*)&Bs[(wc * 32 + j * 16 + lo) * KP + quad * 8];
#pragma unroll
            for (int i = 0; i < 2; i++)
#pragma unroll
                for (int j = 0; j < 2; j++)
                    acc[i][j] = __builtin_amdgcn_mfma_f32_16x16x32_bf16(afr[i], bfr[j], acc[i][j], 0, 0, 0);
        }
        __syncthreads();
        *(bf16x8*)&As[rS * KP + c8] = aR1;
        *(bf16x8*)&Bs[rS * KP + c8] = bR1;
        __syncthreads();
        if (k0 + 3 * BK < DD) {
            aR1 = *(const bf16x8*)(arow + k0 + 3 * BK);
            bR1 = *(const bf16x8*)(wrow + k0 + 3 * BK);
        }
        {
            bf16x8 afr[2], bfr[2];
#pragma unroll
            for (int i = 0; i < 2; i++)
                afr[i] = *(const bf16x8*)&As[(wr * 32 + i * 16 + lo) * KP + quad * 8];
#pragma unroll
            for (int j = 0; j < 2; j++)
                bfr[j] = *(const bf16x8*)&Bs[(wc * 32 + j * 16 + lo) * KP + quad * 8];
#pragma unroll
            for (int i = 0; i < 2; i++)
#pragma unroll
                for (int j = 0; j < 2; j++)
                    acc[i][j] = __builtin_amdgcn_mfma_f32_16x16x32_bf16(afr[i], bfr[j], acc[i][j], 0, 0, 0);
        }
    }

#pragma unroll
    for (int i = 0; i < 2; i++)
#pragma unroll
        for (int j = 0; j < 2; j++)
#pragma unroll
            for (int reg = 0; reg < 4; reg++) {
                int row = rowBase + wr * 32 + i * 16 + quad * 4 + reg;  // token
                int c = wc * 32 + j * 16 + lo;                          // 0..63
                float v = acc[i][j][reg];
                if (cb < 16) {
                    QA[(size_t)row * DD + cb * 64 + c] = (bf16_t)(v * SCALEQ);
                } else if (cb == 16) {
                    Kp[(size_t)row * HD + c] = (bf16_t)v;
                } else {
                    VpT[((size_t)(row >> 11) * HD + c) * SS + (row & (SS - 1))] = (bf16_t)v;
                }
            }
}

__global__ __launch_bounds__(256) void proj_o_b(const bf16_t* __restrict__ AO,
                                                const bf16_t* __restrict__ Wo,
                                                void* __restrict__ Cout,
                                                const int* __restrict__ flagOut) {
    const int fout = *flagOut;

    __shared__ bf16_t As[64 * KP];
    __shared__ bf16_t Bs[64 * KP];

    const int tid = threadIdx.x;
    const int wave = tid >> 6, lane = tid & 63;
    const int lo = lane & 15, quad = lane >> 4;
    const int wr = wave >> 1, wc = wave & 1;
    const int rowBase = blockIdx.x * 64;           // row tile (fastest dim)
    const int colBase = blockIdx.y * 64;

    const int rS = tid >> 2;
    const int c8 = (tid & 3) * 8;

    const bf16_t* arow = AO + (size_t)(rowBase + rS) * DD + c8;
    const bf16_t* wrow = Wo + (size_t)(colBase + rS) * DD + c8;

    floatx4 acc[2][2];
#pragma unroll
    for (int i = 0; i < 2; i++)
#pragma unroll
        for (int j = 0; j < 2; j++) acc[i][j] = (floatx4){0.f, 0.f, 0.f, 0.f};

    bf16x8 aR0 = *(const bf16x8*)(arow);
    bf16x8 bR0 = *(const bf16x8*)(wrow);
    bf16x8 aR1 = *(const bf16x8*)(arow + BK);
    bf16x8 bR1 = *(const bf16x8*)(wrow + BK);

    for (int k0 = 0; k0 < DD; k0 += 2 * BK) {
        __syncthreads();
        *(bf16x8*)&As[rS * KP + c8] = aR0;
        *(bf16x8*)&Bs[rS * KP + c8] = bR0;
        __syncthreads();
        if (k0 + 2 * BK < DD) {
            aR0 = *(const bf16x8*)(arow + k0 + 2 * BK);
            bR0 = *(const bf16x8*)(wrow + k0 + 2 * BK);
        }
        {
            bf16x8 afr[2], bfr[2];
#pragma unroll
            for (int i = 0; i < 2; i++)
                afr[i] = *(const bf16x8*)&As[(wr * 32 + i * 16 + lo) * KP + quad * 8];
#pragma unroll
            for (int j = 0; j < 2; j++)
                bfr[j] = *(const bf16x8*)&Bs[(wc * 32 + j * 16 + lo) * KP + quad * 8];
#pragma unroll
            for (int i = 0; i < 2; i++)
#pragma unroll
                for (int j = 0; j < 2; j++)
                    acc[i][j] = __builtin_amdgcn_mfma_f32_16x16x32_bf16(afr[i], bfr[j], acc[i][j], 0, 0, 0);
        }
        __syncthreads();
        *(bf16x8*)&As[rS * KP + c8] = aR1;
        *(bf16x8*)&Bs[rS * KP + c8] = bR1;
        __syncthreads();
        if (k0 + 3 * BK < DD) {
            aR1 = *(const bf16x8*)(arow + k0 + 3 * BK);
            bR1 = *(const bf16x8*)(wrow + k0 + 3 * BK);
        }
        {
            bf16x8 afr[2], bfr[2];
#pragma unroll
            for (int i = 0; i < 2; i++)
                afr[i] = *(const bf16x8*)&As[(wr * 32 + i * 16 + lo) * KP + quad * 8];
#pragma unroll
            for (int j = 0; j < 2; j++)
                bfr[j] = *(const bf16x8*)&Bs[(wc * 32 + j * 16 + lo) * KP + quad * 8];
#pragma unroll
            for (int i = 0; i < 2; i++)
#pragma unroll
                for (int j = 0; j < 2; j++)
                    acc[i][j] = __builtin_amdgcn_mfma_f32_16x16x32_bf16(afr[i], bfr[j], acc[i][j], 0, 0, 0);
        }
    }

#pragma unroll
    for (int i = 0; i < 2; i++)
#pragma unroll
        for (int j = 0; j < 2; j++)
#pragma unroll
            for (int reg = 0; reg < 4; reg++) {
                int row = rowBase + wr * 32 + i * 16 + quad * 4 + reg;
                int col = colBase + wc * 32 + j * 16 + lo;
                size_t idx = (size_t)row * DD + col;
                if (fout) ((float*)Cout)[idx] = acc[i][j][reg];
                else      ((bf16_t*)Cout)[idx] = (bf16_t)acc[i][j][reg];
            }
}

// -------- fallback bf16 projections (direct input, ws too small) ---------
// Used only when workspace cannot hold the converted operands; inputs are
// then read as bf16 if flag==0, else converted inline per 8-elem group.
__device__ __forceinline__ bf16x8 ld8(const void* p, int f, size_t idx) {
    if (f) {
        const float* q = (const float*)p + idx;
        float4 a = *(const float4*)(q);
        float4 b = *(const float4*)(q + 4);
        bf16x8 o;
        o[0] = (bf16_t)a.x; o[1] = (bf16_t)a.y; o[2] = (bf16_t)a.z; o[3] = (bf16_t)a.w;
        o[4] = (bf16_t)b.x; o[5] = (bf16_t)b.y; o[6] = (bf16_t)b.z; o[7] = (bf16_t)b.w;
        return o;
    }
    return *(const bf16x8*)((const bf16_t*)p + idx);
}

__global__ __launch_bounds__(256) void proj_qkv_f(const void* __restrict__ X,
                                                  const void* __restrict__ Wq,
                                                  const void* __restrict__ Wk,
                                                  const void* __restrict__ Wv,
                                                  bf16_t* __restrict__ QA,
                                                  bf16_t* __restrict__ Kp,
                                                  bf16_t* __restrict__ VpT,
                                                  const int* __restrict__ flag) {
    const int f = *flag;
    __shared__ bf16_t As[64 * KP];
    __shared__ bf16_t Bs[64 * KP];

    const int tid = threadIdx.x;
    const int wave = tid >> 6, lane = tid & 63;
    const int lo = lane & 15, quad = lane >> 4;
    const int wr = wave >> 1, wc = wave & 1;
    const int rowBase = blockIdx.x * 64;
    const int cb = blockIdx.y;

    const int rS = tid >> 2;
    const int c8 = (tid & 3) * 8;

    size_t aidx = (size_t)(rowBase + rS) * DD + c8;
    size_t widx;
    const void* Wsrc;
    if (cb < 16)       { Wsrc = Wq; widx = (size_t)(cb * 64 + rS) * DD + c8; }
    else if (cb == 16) { Wsrc = Wk; widx = (size_t)rS * DD + c8; }
    else               { Wsrc = Wv; widx = (size_t)rS * DD + c8; }

    floatx4 acc[2][2];
#pragma unroll
    for (int i = 0; i < 2; i++)
#pragma unroll
        for (int j = 0; j < 2; j++) acc[i][j] = (floatx4){0.f, 0.f, 0.f, 0.f};

    for (int k0 = 0; k0 < DD; k0 += BK) {
        __syncthreads();
        *(bf16x8*)&As[rS * KP + c8] = ld8(X, f, aidx + k0);
        *(bf16x8*)&Bs[rS * KP + c8] = ld8(Wsrc, f, widx + k0);
        __syncthreads();
        bf16x8 afr[2], bfr[2];
#pragma unroll
        for (int i = 0; i < 2; i++)
            afr[i] = *(const bf16x8*)&As[(wr * 32 + i * 16 + lo) * KP + quad * 8];
#pragma unroll
        for (int j = 0; j < 2; j++)
            bfr[j] = *(const bf16x8*)&Bs[(wc * 32 + j * 16 + lo) * KP + quad * 8];
#pragma unroll
        for (int i = 0; i < 2; i++)
#pragma unroll
            for (int j = 0; j < 2; j++)
                acc[i][j] = __builtin_amdgcn_mfma_f32_16x16x32_bf16(afr[i], bfr[j], acc[i][j], 0, 0, 0);
    }

#pragma unroll
    for (int i = 0; i < 2; i++)
#pragma unroll
        for (int j = 0; j < 2; j++)
#pragma unroll
            for (int reg = 0; reg < 4; reg++) {
                int row = rowBase + wr * 32 + i * 16 + quad * 4 + reg;
                int c = wc * 32 + j * 16 + lo;
                float v = acc[i][j][reg];
                if (cb < 16) {
                    QA[(size_t)row * DD + cb * 64 + c] = (bf16_t)(v * SCALEQ);
                } else if (cb == 16) {
                    Kp[(size_t)row * HD + c] = (bf16_t)v;
                } else {
                    VpT[((size_t)(row >> 11) * HD + c) * SS + (row & (SS - 1))] = (bf16_t)v;
                }
            }
}

__global__ __launch_bounds__(256) void proj_o_f(const bf16_t* __restrict__ AO,
                                                const void* __restrict__ Wo,
                                                void* __restrict__ Cout,
                                                const int* __restrict__ flagW,
                                                const int* __restrict__ flagOut) {
    const int f = *flagW;
    const int fout = *flagOut;
    __shared__ bf16_t As[64 * KP];
    __shared__ bf16_t Bs[64 * KP];

    const int tid = threadIdx.x;
    const int wave = tid >> 6, lane = tid & 63;
    const int lo = lane & 15, quad = lane >> 4;
    const int wr = wave >> 1, wc = wave & 1;
    const int rowBase = blockIdx.x * 64;
    const int colBase = blockIdx.y * 64;

    const int rS = tid >> 2;
    const int c8 = (tid & 3) * 8;

    size_t aidx = (size_t)(rowBase + rS) * DD + c8;
    size_t widx = (size_t)(colBase + rS) * DD + c8;

    floatx4 acc[2][2];
#pragma unroll
    for (int i = 0; i < 2; i++)
#pragma unroll
        for (int j = 0; j < 2; j++) acc[i][j] = (floatx4){0.f, 0.f, 0.f, 0.f};

    for (int k0 = 0; k0 < DD; k0 += BK) {
        __syncthreads();
        *(bf16x8*)&As[rS * KP + c8] = *(const bf16x8*)(AO + aidx + k0);
        *(bf16x8*)&Bs[rS * KP + c8] = ld8(Wo, f, widx + k0);
        __syncthreads();
        bf16x8 afr[2], bfr[2];
#pragma unroll
        for (int i = 0; i < 2; i++)
            afr[i] = *(const bf16x8*)&As[(wr * 32 + i * 16 + lo) * KP + quad * 8];
#pragma unroll
        for (int j = 0; j < 2; j++)
            bfr[j] = *(const bf16x8*)&Bs[(wc * 32 + j * 16 + lo) * KP + quad * 8];
#pragma unroll
        for (int i = 0; i < 2; i++)
#pragma unroll
            for (int j = 0; j < 2; j++)
                acc[i][j] = __builtin_amdgcn_mfma_f32_16x16x32_bf16(afr[i], bfr[j], acc[i][j], 0, 0, 0);
    }

#pragma unroll
    for (int i = 0; i < 2; i++)
#pragma unroll
        for (int j = 0; j < 2; j++)
#pragma unroll
            for (int reg = 0; reg < 4; reg++) {
                int row = rowBase + wr * 32 + i * 16 + quad * 4 + reg;
                int col = colBase + wc * 32 + j * 16 + lo;
                size_t idx = (size_t)row * DD + col;
                if (fout) ((float*)Cout)[idx] = acc[i][j][reg];
                else      ((bf16_t*)Cout)[idx] = (bf16_t)acc[i][j][reg];
            }
}

// ---------------- MFMA flash attention: 4-wave single-q-tile blocks ------
// OCCUPANCY-QUANTIZATION FIX: the wave uses 96 unified regs -> 5 waves/SIMD
// fit, but 8-wave blocks quantize residency to 2 blocks = 16 waves/CU,
// wasting the 5th slot. 4-wave (256-thr) blocks at __launch_bounds__(256,5)
// (102-reg cap >= current 96: no new pressure) give 5 blocks/CU = 20
// waves/CU (+25% TLP on a latency-bound kernel). One q-tile per block; keys
// split evenly over 4 waves; grid (64,NH,BB)=2048 blocks in LPT order
// (qt = 63-bx: longest first — perf heuristic only). 2-round tree merge.
// PROVEN: reg caps below ~96 (64-cap R1, 85-cap R4) spill catastrophically.
#define PSTR 40
#define DMTHR 8.0f    // defer-max threshold (exp2 domain)

__global__ __launch_bounds__(256, 5) void attn_mfma(const bf16_t* Q,
                                                    const bf16_t* __restrict__ K,
                                                    const bf16_t* __restrict__ Vt,
                                                    bf16_t* O) {
    const int h = blockIdx.y, b = blockIdx.z;
    const int tid = threadIdx.x;
    const int wq = tid >> 6, lane = tid & 63;
    const int lo = lane & 15, quad = lane >> 4;
    const int qt = 63 - blockIdx.x;     // LPT: longest q-tiles dispatch first
    const int q0 = qt * 32;
    const int n = qt + 1;               // total key-tiles for this q-tile
    const int itS = (n * wq) >> 2;
    const int itE = (n * (wq + 1)) >> 2;

    // --- LDS: P staging (per-wave, loop phase) unions merge buffers ---
    __shared__ __align__(16) char smem[2 * 32 * 64 * 4];  // 16384 B
    __shared__ float MrgML[2][2][2][16];                  // [buf][s][m/l][lo]
    bf16_t* Pw = (bf16_t*)smem + wq * (32 * PSTR);        // 4 x 2560 B = 10240 B
    float (*MrgO)[32 * 64] = (float (*)[32 * 64])smem;    // 2 bufs x 8 KB

    // Q frags (B operand: n=q, k=dim); Q already scaled by (1/8)*log2(e)
    bf16x8 qf[2][2];
#pragma unroll
    for (int s = 0; s < 2; s++)
#pragma unroll
        for (int hf = 0; hf < 2; hf++)
            qf[s][hf] = *(const bf16x8*)(Q + ((size_t)(b * SS + q0 + s * 16 + lo)) * DD +
                                         h * HD + hf * 32 + quad * 8);

    floatx4 Oacc[2][4];
    float m_i[2], l_ln[2];   // m: column-consistent running max; l: LANE-partial
#pragma unroll
    for (int s = 0; s < 2; s++) {
#pragma unroll
        for (int dt = 0; dt < 4; dt++) Oacc[s][dt] = (floatx4){0.f, 0.f, 0.f, 0.f};
        m_i[s] = -1e30f; l_ln[s] = 0.f;
    }

    const bf16_t* Kb = K + (size_t)b * SS * HD;
    const bf16_t* Vb = Vt + (size_t)b * HD * SS;

    if (itS < itE) {
        // preload K tile itS
        bf16x8 kf[2][2];
#pragma unroll
        for (int kt = 0; kt < 2; kt++)
#pragma unroll
            for (int hf = 0; hf < 2; hf++)
                kf[kt][hf] = *(const bf16x8*)(Kb + (size_t)(itS * 32 + kt * 16 + lo) * HD +
                                              hf * 32 + quad * 8);

        for (int it = itS; it < itE; it++) {
            const int t0 = it * 32;

            bf16x8 vf[4];
#pragma unroll
            for (int dt = 0; dt < 4; dt++)
                vf[dt] = *(const bf16x8*)(Vb + (size_t)(dt * 16 + lo) * SS + t0 + quad * 8);

            bf16x8 kn[2][2];
            if (it + 1 < itE) {
#pragma unroll
                for (int kt = 0; kt < 2; kt++)
#pragma unroll
                    for (int hf = 0; hf < 2; hf++)
                        kn[kt][hf] = *(const bf16x8*)(Kb + (size_t)(t0 + 32 + kt * 16 + lo) * HD +
                                                      hf * 32 + quad * 8);
            }

            // S^T = K.Q^T  (already in exp2 domain via pre-scaled Q)
            floatx4 st[2][2];
#pragma unroll
            for (int s = 0; s < 2; s++)
#pragma unroll
                for (int kt = 0; kt < 2; kt++) {
                    floatx4 z = (floatx4){0.f, 0.f, 0.f, 0.f};
                    z = __builtin_amdgcn_mfma_f32_16x16x32_bf16(kf[kt][0], qf[s][0], z, 0, 0, 0);
                    z = __builtin_amdgcn_mfma_f32_16x16x32_bf16(kf[kt][1], qf[s][1], z, 0, 0, 0);
                    st[s][kt] = z;
                }

            if (it == qt) {  // diagonal tile (last tile of wave 3)
#pragma unroll
                for (int s = 0; s < 2; s++) {
                    int q = q0 + s * 16 + lo;
#pragma unroll
                    for (int kt = 0; kt < 2; kt++)
#pragma unroll
                        for (int reg = 0; reg < 4; reg++)
                            if (t0 + kt * 16 + quad * 4 + reg > q) st[s][kt][reg] = -1e30f;
                }
            }

            // defer-max online softmax: shuffle-free in the common case
#pragma unroll
            for (int s = 0; s < 2; s++) {
                float lm = fmaxf(fmaxf(fmaxf(st[s][0][0], st[s][0][1]), fmaxf(st[s][0][2], st[s][0][3])),
                                 fmaxf(fmaxf(st[s][1][0], st[s][1][1]), fmaxf(st[s][1][2], st[s][1][3])));
                if (__any(lm > m_i[s] + DMTHR)) {
                    float mx = fmaxf(lm, __shfl_xor(lm, 16));
                    mx = fmaxf(mx, __shfl_xor(mx, 32));
                    float mn = fmaxf(m_i[s], mx);
                    float al = exp2f(m_i[s] - mn);
                    m_i[s] = mn;
                    l_ln[s] *= al;
#pragma unroll
                    for (int dt = 0; dt < 4; dt++) Oacc[s][dt] *= al;
                }
                float p[2][4];
#pragma unroll
                for (int kt = 0; kt < 2; kt++)
#pragma unroll
                    for (int reg = 0; reg < 4; reg++)
                        p[kt][reg] = exp2f(st[s][kt][reg] - m_i[s]);
                l_ln[s] += ((p[0][0] + p[0][1]) + (p[0][2] + p[0][3])) +
                           ((p[1][0] + p[1][1]) + (p[1][2] + p[1][3]));
#pragma unroll
                for (int kt = 0; kt < 2; kt++) {
                    bf16x4 pk;
#pragma unroll
                    for (int reg = 0; reg < 4; reg++) pk[reg] = (bf16_t)p[kt][reg];
                    *(bf16x4*)&Pw[(s * 16 + lo) * PSTR + kt * 16 + quad * 4] = pk;
                }
            }

            asm volatile("s_waitcnt lgkmcnt(0)" ::: "memory");

            // O^T += V^T . P^T
            bf16x8 pb[2];
#pragma unroll
            for (int s = 0; s < 2; s++)
                pb[s] = *(const bf16x8*)&Pw[(s * 16 + lo) * PSTR + quad * 8];
#pragma unroll
            for (int s = 0; s < 2; s++)
#pragma unroll
                for (int dt = 0; dt < 4; dt++)
                    Oacc[s][dt] = __builtin_amdgcn_mfma_f32_16x16x32_bf16(vf[dt], pb[s], Oacc[s][dt], 0, 0, 0);

#pragma unroll
            for (int kt = 0; kt < 2; kt++)
#pragma unroll
                for (int hf = 0; hf < 2; hf++) kf[kt][hf] = kn[kt][hf];
        }
    }

    // ---- finalize lane-partial l into column-consistent l_i ----
    float l_i[2];
#pragma unroll
    for (int s = 0; s < 2; s++) {
        float l = l_ln[s];
        l += __shfl_xor(l, 16);
        l += __shfl_xor(l, 32);
        l_i[s] = l;
    }

    // ---- binary-tree merge over 4 waves (flash merge algebra) ----
    // Publishers (wq % 2*step == step) write to buffer wq>>1; combiners
    // fold buffer (wq+step)>>1. Empty waves (itS==itE) publish m=-1e30,
    // l=0, O=0 -> their contribution weights to exactly 0.
    for (int step = 1; step < 4; step <<= 1) {
        const bool pub = (wq & (2 * step - 1)) == step;
        const bool cmb = ((wq & (2 * step - 1)) == 0) && (wq + step < 4);
        __syncthreads();   // previous round's reads (and P-staging use) done
        if (pub) {
            float* Ob = MrgO[wq >> 1];
#pragma unroll
            for (int s = 0; s < 2; s++) {
#pragma unroll
                for (int dt = 0; dt < 4; dt++)
#pragma unroll
                    for (int reg = 0; reg < 4; reg++)
                        Ob[(s * 16 + dt * 4 + reg) * 64 + lane] = Oacc[s][dt][reg];
                if (quad == 0) {
                    MrgML[wq >> 1][s][0][lo] = m_i[s];
                    MrgML[wq >> 1][s][1][lo] = l_i[s];
                }
            }
        }
        __syncthreads();
        if (cmb) {
            const int bu = (wq + step) >> 1;
            const float* Ob = MrgO[bu];
#pragma unroll
            for (int s = 0; s < 2; s++) {
                float m1 = MrgML[bu][s][0][lo];
                float l1 = MrgML[bu][s][1][lo];
                float mm = fmaxf(m_i[s], m1);
                float a0 = exp2f(m_i[s] - mm);
                float a1 = exp2f(m1 - mm);
                m_i[s] = mm;
                l_i[s] = l_i[s] * a0 + l1 * a1;
#pragma unroll
                for (int dt = 0; dt < 4; dt++)
#pragma unroll
                    for (int reg = 0; reg < 4; reg++)
                        Oacc[s][dt][reg] = Oacc[s][dt][reg] * a0 +
                                           Ob[(s * 16 + dt * 4 + reg) * 64 + lane] * a1;
            }
        }
    }

    // ---- wave 0 finalizes + stores ----
    if (wq == 0) {
#pragma unroll
        for (int s = 0; s < 2; s++) {
            float linv = 1.f / l_i[s];
            bf16_t* Orow = O + ((size_t)(b * SS + q0 + s * 16 + lo)) * DD + h * HD;
#pragma unroll
            for (int dt = 0; dt < 4; dt++) {
                bf16x4 ov;
#pragma unroll
                for (int reg = 0; reg < 4; reg++)
                    ov[reg] = (bf16_t)(Oacc[s][dt][reg] * linv);
                *(bf16x4*)&Orow[dt * 16 + quad * 4] = ov;
            }
        }
    }
}

// ---------------- launch ----------------
extern "C" void kernel_launch(void* const* d_in, const int* in_sizes, int n_in,
                              void* d_out, int out_size, void* d_ws, size_t ws_size,
                              hipStream_t stream) {
    const void* x  = d_in[0];
    const void* Wq = d_in[1];
    const void* Wk = d_in[2];
    const void* Wv = d_in[3];
    const void* Wo = d_in[4];
    // d_in[5] = causal mask — known tril, handled analytically in attn_mfma.

    // Workspace layout:
    // [flag 2xint, 256B] | QA bf16[4096,1024] | Kp bf16[4096,64] |
    // VpT bf16[2][64][2048] | Xb bf16[4096,1024] | Wqb bf16[1024,1024] |
    // Wkb bf16[64,1024] | Wvb bf16[64,1024] | Wob bf16[1024,1024]
    char* ws = (char*)d_ws;
    int* flag = (int*)ws;
    bf16_t* QA  = (bf16_t*)(ws + 256);
    bf16_t* Kp  = QA + (size_t)MM * DD;
    bf16_t* VpT = Kp + (size_t)MM * HD;
    bf16_t* Xb  = VpT + (size_t)BB * HD * SS;
    bf16_t* Wqb = Xb + (size_t)MM * DD;
    bf16_t* Wkb = Wqb + (size_t)DD * DD;
    bf16_t* Wvb = Wkb + (size_t)HD * DD;
    bf16_t* Wob = Wvb + (size_t)HD * DD;
    size_t need = (size_t)((char*)(Wob + (size_t)DD * DD) - ws);

    detect_dtype<<<1, 64, 0, stream>>>((const unsigned int*)x, flag);

    if (ws_size >= need) {
        // Convert all operands to bf16 once; projections run the 64x64-tile
        // bf16-only path (256 thr, depth-2 prefetch, 1152/1024 blocks).
        conv_all<<<dim3(1024), dim3(256), 0, stream>>>(x, Wq, Wk, Wv, Wo,
                                                       Xb, Wqb, Wkb, Wvb, Wob, flag);
        proj_qkv_b<<<dim3(MM / 64, 18), dim3(256), 0, stream>>>(Xb, Wqb, Wkb, Wvb,
                                                                QA, Kp, VpT);
        attn_mfma<<<dim3(64, NH, BB), dim3(256), 0, stream>>>(QA, Kp, VpT, QA);
        proj_o_b<<<dim3(MM / 64, 16), dim3(256), 0, stream>>>(QA, Wob, d_out, flag);
    } else {
        // Fallback: direct-from-input 64x64 path (inline cvt when fp32).
        proj_qkv_f<<<dim3(MM / 64, 18), dim3(256), 0, stream>>>(x, Wq, Wk, Wv,
                                                                QA, Kp, VpT, flag);
        attn_mfma<<<dim3(64, NH, BB), dim3(256), 0, stream>>>(QA, Kp, VpT, QA);
        proj_o_f<<<dim3(MM / 64, 16), dim3(256), 0, stream>>>(QA, Wo, d_out,
                                                              flag, flag);
    }
}

// Round 13
// 207.141 us; speedup vs baseline: 1.7688x; 1.7688x over previous
//
#include <hip/hip_runtime.h>
#include <hip/hip_bf16.h>
#include <math.h>

// Problem constants (MultiQueryAttention: B=2, S=2048, D=1024, H=16, hd=64)
#define BB 2
#define SS 2048
#define DD 1024
#define NH 16
#define HD 64
#define MM (BB * SS)  // 4096 tokens

#define BK 64            // GEMM k-step (main path)
#define BKF 32           // fallback k-step

typedef __hip_bfloat16 bf16;
typedef __bf16 bf16_t;
typedef __attribute__((ext_vector_type(8))) __bf16 bf16x8;
typedef __attribute__((ext_vector_type(4))) __bf16 bf16x4;
typedef __attribute__((ext_vector_type(4))) float floatx4;

// (1/sqrt(64)) * log2(e): folded into Q at projection time so QK^T scores
// come out directly in the exp2 domain.
#define SCALEQ 0.18033688011112042f

// bf16-plausibility check for one 32-bit word's low half (as bf16 bits)
__device__ __forceinline__ int bf16_plausible(unsigned int w) {
    unsigned int bits = (w & 0xFFFFu) << 16;
    float v = __uint_as_float(bits);
    float av = fabsf(v);
    return (av == 0.f || (av >= 9.5367431640625e-7f && av <= 64.f)) ? 1 : 0;
}

// ---------------- runtime dtype detection (standalone, fallback path) ----
// flag[0]==1 -> external tensors are fp32; flag[0]==0 -> bf16.
__global__ void detect_dtype(const unsigned int* __restrict__ x, int* __restrict__ flag) {
    const int tid = threadIdx.x;  // 64 lanes
    int good = 0;
    for (int i = tid; i < 256; i += 64) good += bf16_plausible(x[i]);
#pragma unroll
    for (int s = 1; s < 64; s <<= 1) good += __shfl_xor(good, s);
    if (tid == 0) { flag[0] = (good >= 240) ? 0 : 1; flag[1] = 0; }
}

// ---------------- bulk fp32->bf16 conversion + fused dtype detection -----
// Each block classifies x[0..255] locally (L2-hot, ~20 insts) and uses its
// own verdict — removes the serialized detect_dtype launch from the main
// path. Block 0 publishes flag for the downstream proj_o_b fout read
// (stream order guarantees visibility).
__device__ __forceinline__ void conv_seg(const void* __restrict__ in,
                                         bf16_t* __restrict__ out,
                                         int n, int f, int tid, int T) {
    if (f) {
        const float* p = (const float*)in;
        for (int i = tid * 8; i < n; i += T * 8) {
            float4 a = *(const float4*)(p + i);
            float4 b = *(const float4*)(p + i + 4);
            bf16x8 o;
            o[0] = (bf16_t)a.x; o[1] = (bf16_t)a.y; o[2] = (bf16_t)a.z; o[3] = (bf16_t)a.w;
            o[4] = (bf16_t)b.x; o[5] = (bf16_t)b.y; o[6] = (bf16_t)b.z; o[7] = (bf16_t)b.w;
            *(bf16x8*)(out + i) = o;
        }
    } else {
        const bf16_t* p = (const bf16_t*)in;
        for (int i = tid * 8; i < n; i += T * 8)
            *(bf16x8*)(out + i) = *(const bf16x8*)(p + i);
    }
}

__global__ __launch_bounds__(256) void conv_all(const void* __restrict__ x,
                                                const void* __restrict__ wq,
                                                const void* __restrict__ wk,
                                                const void* __restrict__ wv,
                                                const void* __restrict__ wo,
                                                bf16_t* __restrict__ xb,
                                                bf16_t* __restrict__ wqb,
                                                bf16_t* __restrict__ wkb,
                                                bf16_t* __restrict__ wvb,
                                                bf16_t* __restrict__ wob,
                                                int* __restrict__ flag) {
    __shared__ int goodw[4];
    const int ltid = threadIdx.x;
    // per-block detection: thread t checks element t of x (256 elems)
    int g = bf16_plausible(((const unsigned int*)x)[ltid]);
#pragma unroll
    for (int s = 1; s < 64; s <<= 1) g += __shfl_xor(g, s);
    if ((ltid & 63) == 0) goodw[ltid >> 6] = g;
    __syncthreads();
    const int good = goodw[0] + goodw[1] + goodw[2] + goodw[3];
    const int f = (good >= 240) ? 0 : 1;
    if (blockIdx.x == 0 && ltid == 0) { flag[0] = f; flag[1] = 0; }

    const int tid = blockIdx.x * blockDim.x + ltid;
    const int T = gridDim.x * blockDim.x;
    conv_seg(x, xb, MM * DD, f, tid, T);
    conv_seg(wq, wqb, DD * DD, f, tid, T);
    conv_seg(wk, wkb, HD * DD, f, tid, T);
    conv_seg(wv, wvb, HD * DD, f, tid, T);
    conv_seg(wo, wob, DD * DD, f, tid, T);
}

// ------- 128x128-tile bf16 projection GEMMs (512 thr, BK=64, depth-2) ----
// 8 waves in 2x4; each wave owns 64x32 with acc[4][2] and 16 MFMA/k-step
// (2 kk-substeps of K=32). Depth-2 NAMED register prefetch (~2 k-steps of
// latency cover; proven vs 1-deep global_load_lds which regressed). KP2=72
// row stride: 144 B == 4 (mod 128) -> conflict-free b128 reads. Transposed
// grid (row-tile fastest): consecutive blocks share one weight panel and
// spread X row-panels across XCDs (T1). BEST MEASURED CONFIG (R9: 208.7us).
#define KP2 72

__global__ __launch_bounds__(512) void proj_qkv_b(const bf16_t* __restrict__ X,
                                                  const bf16_t* __restrict__ Wq,
                                                  const bf16_t* __restrict__ Wk,
                                                  const bf16_t* __restrict__ Wv,
                                                  bf16_t* __restrict__ QA,
                                                  bf16_t* __restrict__ Kp,
                                                  bf16_t* __restrict__ VpT) {
    __shared__ bf16_t As[128 * KP2];
    __shared__ bf16_t Bs[128 * KP2];

    const int tid = threadIdx.x;
    const int wave = tid >> 6, lane = tid & 63;
    const int lo = lane & 15, quad = lane >> 4;
    const int wr = wave >> 2, wc = wave & 3;       // 2x4 wave grid
    const int rowBase = blockIdx.x * 128;          // row tile (fastest dim)
    const int cb = blockIdx.y;                     // 0..8 (8 => K|V fused)

    const int rS = tid >> 2;           // 0..127
    const int c16 = (tid & 3) * 16;    // 0,16,32,48

    const bf16_t* arow = X + (size_t)(rowBase + rS) * DD + c16;
    const bf16_t* wrow;
    if (cb < 8)       wrow = Wq + (size_t)(cb * 128 + rS) * DD + c16;
    else if (rS < 64) wrow = Wk + (size_t)rS * DD + c16;
    else              wrow = Wv + (size_t)(rS - 64) * DD + c16;

    floatx4 acc[4][2];
#pragma unroll
    for (int i = 0; i < 4; i++)
#pragma unroll
        for (int j = 0; j < 2; j++) acc[i][j] = (floatx4){0.f, 0.f, 0.f, 0.f};

    // depth-2 prefetch: two NAMED register sets (no runtime indexing)
    bf16x8 aR0[2], bR0[2], aR1[2], bR1[2];
#pragma unroll
    for (int p = 0; p < 2; p++) {
        aR0[p] = *(const bf16x8*)(arow + p * 8);
        bR0[p] = *(const bf16x8*)(wrow + p * 8);
        aR1[p] = *(const bf16x8*)(arow + BK + p * 8);
        bR1[p] = *(const bf16x8*)(wrow + BK + p * 8);
    }

    for (int k0 = 0; k0 < DD; k0 += 2 * BK) {
        // ---- sub-step A: tile k0 (set 0) ----
        __syncthreads();
#pragma unroll
        for (int p = 0; p < 2; p++) {
            *(bf16x8*)&As[rS * KP2 + c16 + p * 8] = aR0[p];
            *(bf16x8*)&Bs[rS * KP2 + c16 + p * 8] = bR0[p];
        }
        __syncthreads();
        if (k0 + 2 * BK < DD) {
#pragma unroll
            for (int p = 0; p < 2; p++) {
                aR0[p] = *(const bf16x8*)(arow + k0 + 2 * BK + p * 8);
                bR0[p] = *(const bf16x8*)(wrow + k0 + 2 * BK + p * 8);
            }
        }
#pragma unroll
        for (int kk = 0; kk < 2; kk++) {
            bf16x8 afr[4], bfr[2];
#pragma unroll
            for (int i = 0; i < 4; i++)
                afr[i] = *(const bf16x8*)&As[(wr * 64 + i * 16 + lo) * KP2 + kk * 32 + quad * 8];
#pragma unroll
            for (int j = 0; j < 2; j++)
                bfr[j] = *(const bf16x8*)&Bs[(wc * 32 + j * 16 + lo) * KP2 + kk * 32 + quad * 8];
#pragma unroll
            for (int i = 0; i < 4; i++)
#pragma unroll
                for (int j = 0; j < 2; j++)
                    acc[i][j] = __builtin_amdgcn_mfma_f32_16x16x32_bf16(afr[i], bfr[j], acc[i][j], 0, 0, 0);
        }
        // ---- sub-step B: tile k0+BK (set 1) ----
        __syncthreads();
#pragma unroll
        for (int p = 0; p < 2; p++) {
            *(bf16x8*)&As[rS * KP2 + c16 + p * 8] = aR1[p];
            *(bf16x8*)&Bs[rS * KP2 + c16 + p * 8] = bR1[p];
        }
        __syncthreads();
        if (k0 + 3 * BK < DD) {
#pragma unroll
            for (int p = 0; p < 2; p++) {
                aR1[p] = *(const bf16x8*)(arow + k0 + 3 * BK + p * 8);
                bR1[p] = *(const bf16x8*)(wrow + k0 + 3 * BK + p * 8);
            }
        }
#pragma unroll
        for (int kk = 0; kk < 2; kk++) {
            bf16x8 afr[4], bfr[2];
#pragma unroll
            for (int i = 0; i < 4; i++)
                afr[i] = *(const bf16x8*)&As[(wr * 64 + i * 16 + lo) * KP2 + kk * 32 + quad * 8];
#pragma unroll
            for (int j = 0; j < 2; j++)
                bfr[j] = *(const bf16x8*)&Bs[(wc * 32 + j * 16 + lo) * KP2 + kk * 32 + quad * 8];
#pragma unroll
            for (int i = 0; i < 4; i++)
#pragma unroll
                for (int j = 0; j < 2; j++)
                    acc[i][j] = __builtin_amdgcn_mfma_f32_16x16x32_bf16(afr[i], bfr[j], acc[i][j], 0, 0, 0);
        }
    }

#pragma unroll
    for (int i = 0; i < 4; i++)
#pragma unroll
        for (int j = 0; j < 2; j++)
#pragma unroll
            for (int reg = 0; reg < 4; reg++) {
                int row = rowBase + wr * 64 + i * 16 + quad * 4 + reg;  // token
                int c = wc * 32 + j * 16 + lo;                          // 0..127
                float v = acc[i][j][reg];
                if (cb < 8) {
                    QA[(size_t)row * DD + cb * 128 + c] = (bf16_t)(v * SCALEQ);
                } else if (c < 64) {
                    Kp[(size_t)row * HD + c] = (bf16_t)v;
                } else {
                    VpT[((size_t)(row >> 11) * HD + (c - 64)) * SS + (row & (SS - 1))] = (bf16_t)v;
                }
            }
}

__global__ __launch_bounds__(512) void proj_o_b(const bf16_t* __restrict__ AO,
                                                const bf16_t* __restrict__ Wo,
                                                void* __restrict__ Cout,
                                                const int* __restrict__ flagOut) {
    const int fout = *flagOut;

    __shared__ bf16_t As[128 * KP2];
    __shared__ bf16_t Bs[128 * KP2];

    const int tid = threadIdx.x;
    const int wave = tid >> 6, lane = tid & 63;
    const int lo = lane & 15, quad = lane >> 4;
    const int wr = wave >> 2, wc = wave & 3;
    const int rowBase = blockIdx.x * 128;          // row tile (fastest dim)
    const int colBase = blockIdx.y * 128;

    const int rS = tid >> 2;
    const int c16 = (tid & 3) * 16;

    const bf16_t* arow = AO + (size_t)(rowBase + rS) * DD + c16;
    const bf16_t* wrow = Wo + (size_t)(colBase + rS) * DD + c16;

    floatx4 acc[4][2];
#pragma unroll
    for (int i = 0; i < 4; i++)
#pragma unroll
        for (int j = 0; j < 2; j++) acc[i][j] = (floatx4){0.f, 0.f, 0.f, 0.f};

    bf16x8 aR0[2], bR0[2], aR1[2], bR1[2];
#pragma unroll
    for (int p = 0; p < 2; p++) {
        aR0[p] = *(const bf16x8*)(arow + p * 8);
        bR0[p] = *(const bf16x8*)(wrow + p * 8);
        aR1[p] = *(const bf16x8*)(arow + BK + p * 8);
        bR1[p] = *(const bf16x8*)(wrow + BK + p * 8);
    }

    for (int k0 = 0; k0 < DD; k0 += 2 * BK) {
        __syncthreads();
#pragma unroll
        for (int p = 0; p < 2; p++) {
            *(bf16x8*)&As[rS * KP2 + c16 + p * 8] = aR0[p];
            *(bf16x8*)&Bs[rS * KP2 + c16 + p * 8] = bR0[p];
        }
        __syncthreads();
        if (k0 + 2 * BK < DD) {
#pragma unroll
            for (int p = 0; p < 2; p++) {
                aR0[p] = *(const bf16x8*)(arow + k0 + 2 * BK + p * 8);
                bR0[p] = *(const bf16x8*)(wrow + k0 + 2 * BK + p * 8);
            }
        }
#pragma unroll
        for (int kk = 0; kk < 2; kk++) {
            bf16x8 afr[4], bfr[2];
#pragma unroll
            for (int i = 0; i < 4; i++)
                afr[i] = *(const bf16x8*)&As[(wr * 64 + i * 16 + lo) * KP2 + kk * 32 + quad * 8];
#pragma unroll
            for (int j = 0; j < 2; j++)
                bfr[j] = *(const bf16x8*)&Bs[(wc * 32 + j * 16 + lo) * KP2 + kk * 32 + quad * 8];
#pragma unroll
            for (int i = 0; i < 4; i++)
#pragma unroll
                for (int j = 0; j < 2; j++)
                    acc[i][j] = __builtin_amdgcn_mfma_f32_16x16x32_bf16(afr[i], bfr[j], acc[i][j], 0, 0, 0);
        }
        __syncthreads();
#pragma unroll
        for (int p = 0; p < 2; p++) {
            *(bf16x8*)&As[rS * KP2 + c16 + p * 8] = aR1[p];
            *(bf16x8*)&Bs[rS * KP2 + c16 + p * 8] = bR1[p];
        }
        __syncthreads();
        if (k0 + 3 * BK < DD) {
#pragma unroll
            for (int p = 0; p < 2; p++) {
                aR1[p] = *(const bf16x8*)(arow + k0 + 3 * BK + p * 8);
                bR1[p] = *(const bf16x8*)(wrow + k0 + 3 * BK + p * 8);
            }
        }
#pragma unroll
        for (int kk = 0; kk < 2; kk++) {
            bf16x8 afr[4], bfr[2];
#pragma unroll
            for (int i = 0; i < 4; i++)
                afr[i] = *(const bf16x8*)&As[(wr * 64 + i * 16 + lo) * KP2 + kk * 32 + quad * 8];
#pragma unroll
            for (int j = 0; j < 2; j++)
                bfr[j] = *(const bf16x8*)&Bs[(wc * 32 + j * 16 + lo) * KP2 + kk * 32 + quad * 8];
#pragma unroll
            for (int i = 0; i < 4; i++)
#pragma unroll
                for (int j = 0; j < 2; j++)
                    acc[i][j] = __builtin_amdgcn_mfma_f32_16x16x32_bf16(afr[i], bfr[j], acc[i][j], 0, 0, 0);
        }
    }

#pragma unroll
    for (int i = 0; i < 4; i++)
#pragma unroll
        for (int j = 0; j < 2; j++)
#pragma unroll
            for (int reg = 0; reg < 4; reg++) {
                int row = rowBase + wr * 64 + i * 16 + quad * 4 + reg;
                int col = colBase + wc * 32 + j * 16 + lo;
                size_t idx = (size_t)row * DD + col;
                if (fout) ((float*)Cout)[idx] = acc[i][j][reg];
                else      ((bf16_t*)Cout)[idx] = (bf16_t)acc[i][j][reg];
            }
}

// -------- fallback projections (direct input, ws too small) --------------
#define KP 40

__device__ __forceinline__ bf16x8 ld8(const void* p, int f, size_t idx) {
    if (f) {
        const float* q = (const float*)p + idx;
        float4 a = *(const float4*)(q);
        float4 b = *(const float4*)(q + 4);
        bf16x8 o;
        o[0] = (bf16_t)a.x; o[1] = (bf16_t)a.y; o[2] = (bf16_t)a.z; o[3] = (bf16_t)a.w;
        o[4] = (bf16_t)b.x; o[5] = (bf16_t)b.y; o[6] = (bf16_t)b.z; o[7] = (bf16_t)b.w;
        return o;
    }
    return *(const bf16x8*)((const bf16_t*)p + idx);
}

__global__ __launch_bounds__(256) void proj_qkv_f(const void* __restrict__ X,
                                                  const void* __restrict__ Wq,
                                                  const void* __restrict__ Wk,
                                                  const void* __restrict__ Wv,
                                                  bf16_t* __restrict__ QA,
                                                  bf16_t* __restrict__ Kp,
                                                  bf16_t* __restrict__ VpT,
                                                  const int* __restrict__ flag) {
    const int f = *flag;
    __shared__ bf16_t As[64 * KP];
    __shared__ bf16_t Bs[64 * KP];

    const int tid = threadIdx.x;
    const int wave = tid >> 6, lane = tid & 63;
    const int lo = lane & 15, quad = lane >> 4;
    const int wr = wave >> 1, wc = wave & 1;
    const int rowBase = blockIdx.x * 64;
    const int cb = blockIdx.y;

    const int rS = tid >> 2;
    const int c8 = (tid & 3) * 8;

    size_t aidx = (size_t)(rowBase + rS) * DD + c8;
    size_t widx;
    const void* Wsrc;
    if (cb < 16)       { Wsrc = Wq; widx = (size_t)(cb * 64 + rS) * DD + c8; }
    else if (cb == 16) { Wsrc = Wk; widx = (size_t)rS * DD + c8; }
    else               { Wsrc = Wv; widx = (size_t)rS * DD + c8; }

    floatx4 acc[2][2];
#pragma unroll
    for (int i = 0; i < 2; i++)
#pragma unroll
        for (int j = 0; j < 2; j++) acc[i][j] = (floatx4){0.f, 0.f, 0.f, 0.f};

    for (int k0 = 0; k0 < DD; k0 += BKF) {
        __syncthreads();
        *(bf16x8*)&As[rS * KP + c8] = ld8(X, f, aidx + k0);
        *(bf16x8*)&Bs[rS * KP + c8] = ld8(Wsrc, f, widx + k0);
        __syncthreads();
        bf16x8 afr[2], bfr[2];
#pragma unroll
        for (int i = 0; i < 2; i++)
            afr[i] = *(const bf16x8*)&As[(wr * 32 + i * 16 + lo) * KP + quad * 8];
#pragma unroll
        for (int j = 0; j < 2; j++)
            bfr[j] = *(const bf16x8*)&Bs[(wc * 32 + j * 16 + lo) * KP + quad * 8];
#pragma unroll
        for (int i = 0; i < 2; i++)
#pragma unroll
            for (int j = 0; j < 2; j++)
                acc[i][j] = __builtin_amdgcn_mfma_f32_16x16x32_bf16(afr[i], bfr[j], acc[i][j], 0, 0, 0);
    }

#pragma unroll
    for (int i = 0; i < 2; i++)
#pragma unroll
        for (int j = 0; j < 2; j++)
#pragma unroll
            for (int reg = 0; reg < 4; reg++) {
                int row = rowBase + wr * 32 + i * 16 + quad * 4 + reg;
                int c = wc * 32 + j * 16 + lo;
                float v = acc[i][j][reg];
                if (cb < 16) {
                    QA[(size_t)row * DD + cb * 64 + c] = (bf16_t)(v * SCALEQ);
                } else if (cb == 16) {
                    Kp[(size_t)row * HD + c] = (bf16_t)v;
                } else {
                    VpT[((size_t)(row >> 11) * HD + c) * SS + (row & (SS - 1))] = (bf16_t)v;
                }
            }
}

__global__ __launch_bounds__(256) void proj_o_f(const bf16_t* __restrict__ AO,
                                                const void* __restrict__ Wo,
                                                void* __restrict__ Cout,
                                                const int* __restrict__ flagW,
                                                const int* __restrict__ flagOut) {
    const int f = *flagW;
    const int fout = *flagOut;
    __shared__ bf16_t As[64 * KP];
    __shared__ bf16_t Bs[64 * KP];

    const int tid = threadIdx.x;
    const int wave = tid >> 6, lane = tid & 63;
    const int lo = lane & 15, quad = lane >> 4;
    const int wr = wave >> 1, wc = wave & 1;
    const int rowBase = blockIdx.x * 64;
    const int colBase = blockIdx.y * 64;

    const int rS = tid >> 2;
    const int c8 = (tid & 3) * 8;

    size_t aidx = (size_t)(rowBase + rS) * DD + c8;
    size_t widx = (size_t)(colBase + rS) * DD + c8;

    floatx4 acc[2][2];
#pragma unroll
    for (int i = 0; i < 2; i++)
#pragma unroll
        for (int j = 0; j < 2; j++) acc[i][j] = (floatx4){0.f, 0.f, 0.f, 0.f};

    for (int k0 = 0; k0 < DD; k0 += BKF) {
        __syncthreads();
        *(bf16x8*)&As[rS * KP + c8] = *(const bf16x8*)(AO + aidx + k0);
        *(bf16x8*)&Bs[rS * KP + c8] = ld8(Wo, f, widx + k0);
        __syncthreads();
        bf16x8 afr[2], bfr[2];
#pragma unroll
        for (int i = 0; i < 2; i++)
            afr[i] = *(const bf16x8*)&As[(wr * 32 + i * 16 + lo) * KP + quad * 8];
#pragma unroll
        for (int j = 0; j < 2; j++)
            bfr[j] = *(const bf16x8*)&Bs[(wc * 32 + j * 16 + lo) * KP + quad * 8];
#pragma unroll
        for (int i = 0; i < 2; i++)
#pragma unroll
            for (int j = 0; j < 2; j++)
                acc[i][j] = __builtin_amdgcn_mfma_f32_16x16x32_bf16(afr[i], bfr[j], acc[i][j], 0, 0, 0);
    }

#pragma unroll
    for (int i = 0; i < 2; i++)
#pragma unroll
        for (int j = 0; j < 2; j++)
#pragma unroll
            for (int reg = 0; reg < 4; reg++) {
                int row = rowBase + wr * 32 + i * 16 + quad * 4 + reg;
                int col = colBase + wc * 32 + j * 16 + lo;
                size_t idx = (size_t)row * DD + col;
                if (fout) ((float*)Cout)[idx] = acc[i][j][reg];
                else      ((bf16_t*)Cout)[idx] = (bf16_t)acc[i][j][reg];
            }
}

// ---------------- barrier-free MFMA flash attention, balanced key-split ----
// 512-thread blocks (8 waves), pair (x, 63-x): 65 key-tiles per block by
// construction; waves assigned proportionally (worst ~10 tiles). Defer-max
// softmax (shuffle-free common case). __launch_bounds__(512, 4): full
// 128-reg bin. PROVEN (3 experiments): reg caps 64/85/102 ALL spill
// catastrophically (0.1-1.5 GB scratch); the wave's live set is >102 and
// <=128 unified regs. This kernel is pinned at 4 waves/SIMD — do not touch
// launch bounds again.
#define PSTR 40
#define DMTHR 8.0f    // defer-max threshold (exp2 domain)

__global__ __launch_bounds__(512, 4) void attn_mfma(const bf16_t* Q,
                                                    const bf16_t* __restrict__ K,
                                                    const bf16_t* __restrict__ Vt,
                                                    bf16_t* O) {
    const int h = blockIdx.y, b = blockIdx.z;
    const int tid = threadIdx.x;
    const int wq = tid >> 6, lane = tid & 63;
    const int lo = lane & 15, quad = lane >> 4;
    const int x = blockIdx.x;           // 0..31 -> pair (x, 63-x)

    // --- proportional wave->q-tile assignment (minimize max wave tiles) ---
    const int nA = x + 1;               // key-tiles for qt = x (pair total 65)
    int na = 1, bestc = 0x7fffffff;
#pragma unroll
    for (int a = 1; a <= 7; ++a) {
        int cA = (nA + a - 1) / a;
        int cB = (65 - nA + (7 - a)) / (8 - a);
        int c = cA > cB ? cA : cB;
        if (c < bestc) { bestc = c; na = a; }
    }
    int qt, pos, gs;
    if (wq < na) { qt = x;      pos = wq;      gs = na; }
    else         { qt = 63 - x; pos = wq - na; gs = 8 - na; }
    const int q0 = qt * 32;
    const int n = qt + 1;               // total key-tiles for this q-tile
    const int itS = (n * pos) / gs;
    const int itE = (n * (pos + 1)) / gs;

    // --- LDS: P staging (per-wave, loop phase) unions merge buffers ---
    __shared__ __align__(16) char smem[4 * 32 * 64 * 4];  // 32768 B
    __shared__ float MrgML[4][2][2][16];                  // [buf][s][m/l][lo]
    bf16_t* Pw = (bf16_t*)smem + wq * (32 * PSTR);        // 8 x 2560 B = 20480 B
    float (*MrgO)[32 * 64] = (float (*)[32 * 64])smem;    // 4 bufs x 8 KB

    // Q frags (B operand: n=q, k=dim); Q already scaled by (1/8)*log2(e)
    bf16x8 qf[2][2];
#pragma unroll
    for (int s = 0; s < 2; s++)
#pragma unroll
        for (int hf = 0; hf < 2; hf++)
            qf[s][hf] = *(const bf16x8*)(Q + ((size_t)(b * SS + q0 + s * 16 + lo)) * DD +
                                         h * HD + hf * 32 + quad * 8);

    floatx4 Oacc[2][4];
    float m_i[2], l_ln[2];   // m: column-consistent running max; l: LANE-partial
#pragma unroll
    for (int s = 0; s < 2; s++) {
#pragma unroll
        for (int dt = 0; dt < 4; dt++) Oacc[s][dt] = (floatx4){0.f, 0.f, 0.f, 0.f};
        m_i[s] = -1e30f; l_ln[s] = 0.f;
    }

    const bf16_t* Kb = K + (size_t)b * SS * HD;
    const bf16_t* Vb = Vt + (size_t)b * HD * SS;

    if (itS < itE) {
        // preload K tile itS
        bf16x8 kf[2][2];
#pragma unroll
        for (int kt = 0; kt < 2; kt++)
#pragma unroll
            for (int hf = 0; hf < 2; hf++)
                kf[kt][hf] = *(const bf16x8*)(Kb + (size_t)(itS * 32 + kt * 16 + lo) * HD +
                                              hf * 32 + quad * 8);

        for (int it = itS; it < itE; it++) {
            const int t0 = it * 32;

            bf16x8 vf[4];
#pragma unroll
            for (int dt = 0; dt < 4; dt++)
                vf[dt] = *(const bf16x8*)(Vb + (size_t)(dt * 16 + lo) * SS + t0 + quad * 8);

            bf16x8 kn[2][2];
            if (it + 1 < itE) {
#pragma unroll
                for (int kt = 0; kt < 2; kt++)
#pragma unroll
                    for (int hf = 0; hf < 2; hf++)
                        kn[kt][hf] = *(const bf16x8*)(Kb + (size_t)(t0 + 32 + kt * 16 + lo) * HD +
                                                      hf * 32 + quad * 8);
            }

            // S^T = K.Q^T  (already in exp2 domain via pre-scaled Q)
            floatx4 st[2][2];
#pragma unroll
            for (int s = 0; s < 2; s++)
#pragma unroll
                for (int kt = 0; kt < 2; kt++) {
                    floatx4 z = (floatx4){0.f, 0.f, 0.f, 0.f};
                    z = __builtin_amdgcn_mfma_f32_16x16x32_bf16(kf[kt][0], qf[s][0], z, 0, 0, 0);
                    z = __builtin_amdgcn_mfma_f32_16x16x32_bf16(kf[kt][1], qf[s][1], z, 0, 0, 0);
                    st[s][kt] = z;
                }

            if (it == qt) {  // diagonal tile (always last pos of the group)
#pragma unroll
                for (int s = 0; s < 2; s++) {
                    int q = q0 + s * 16 + lo;
#pragma unroll
                    for (int kt = 0; kt < 2; kt++)
#pragma unroll
                        for (int reg = 0; reg < 4; reg++)
                            if (t0 + kt * 16 + quad * 4 + reg > q) st[s][kt][reg] = -1e30f;
                }
            }

            // defer-max online softmax: shuffle-free in the common case
#pragma unroll
            for (int s = 0; s < 2; s++) {
                float lm = fmaxf(fmaxf(fmaxf(st[s][0][0], st[s][0][1]), fmaxf(st[s][0][2], st[s][0][3])),
                                 fmaxf(fmaxf(st[s][1][0], st[s][1][1]), fmaxf(st[s][1][2], st[s][1][3])));
                if (__any(lm > m_i[s] + DMTHR)) {
                    float mx = fmaxf(lm, __shfl_xor(lm, 16));
                    mx = fmaxf(mx, __shfl_xor(mx, 32));
                    float mn = fmaxf(m_i[s], mx);
                    float al = exp2f(m_i[s] - mn);
                    m_i[s] = mn;
                    l_ln[s] *= al;
#pragma unroll
                    for (int dt = 0; dt < 4; dt++) Oacc[s][dt] *= al;
                }
                float p[2][4];
#pragma unroll
                for (int kt = 0; kt < 2; kt++)
#pragma unroll
                    for (int reg = 0; reg < 4; reg++)
                        p[kt][reg] = exp2f(st[s][kt][reg] - m_i[s]);
                l_ln[s] += ((p[0][0] + p[0][1]) + (p[0][2] + p[0][3])) +
                           ((p[1][0] + p[1][1]) + (p[1][2] + p[1][3]));
#pragma unroll
                for (int kt = 0; kt < 2; kt++) {
                    bf16x4 pk;
#pragma unroll
                    for (int reg = 0; reg < 4; reg++) pk[reg] = (bf16_t)p[kt][reg];
                    *(bf16x4*)&Pw[(s * 16 + lo) * PSTR + kt * 16 + quad * 4] = pk;
                }
            }

            asm volatile("s_waitcnt lgkmcnt(0)" ::: "memory");

            // O^T += V^T . P^T
            bf16x8 pb[2];
#pragma unroll
            for (int s = 0; s < 2; s++)
                pb[s] = *(const bf16x8*)&Pw[(s * 16 + lo) * PSTR + quad * 8];
#pragma unroll
            for (int s = 0; s < 2; s++)
#pragma unroll
                for (int dt = 0; dt < 4; dt++)
                    Oacc[s][dt] = __builtin_amdgcn_mfma_f32_16x16x32_bf16(vf[dt], pb[s], Oacc[s][dt], 0, 0, 0);

#pragma unroll
            for (int kt = 0; kt < 2; kt++)
#pragma unroll
                for (int hf = 0; hf < 2; hf++) kf[kt][hf] = kn[kt][hf];
        }
    }

    // ---- finalize lane-partial l into column-consistent l_i ----
    float l_i[2];
#pragma unroll
    for (int s = 0; s < 2; s++) {
        float l = l_ln[s];
        l += __shfl_xor(l, 16);
        l += __shfl_xor(l, 32);
        l_i[s] = l;
    }

    // ---- binary-tree merge within each wave group (flash merge algebra) ----
    for (int step = 1; step < 8; step <<= 1) {
        const bool pub = (pos & (2 * step - 1)) == step;
        const bool cmb = ((pos & (2 * step - 1)) == 0) && (pos + step < gs);
        __syncthreads();   // previous round's reads (and P-staging use) done
        if (pub) {
            float* Ob = MrgO[wq >> 1];
#pragma unroll
            for (int s = 0; s < 2; s++) {
#pragma unroll
                for (int dt = 0; dt < 4; dt++)
#pragma unroll
                    for (int reg = 0; reg < 4; reg++)
                        Ob[(s * 16 + dt * 4 + reg) * 64 + lane] = Oacc[s][dt][reg];
                if (quad == 0) {
                    MrgML[wq >> 1][s][0][lo] = m_i[s];
                    MrgML[wq >> 1][s][1][lo] = l_i[s];
                }
            }
        }
        __syncthreads();
        if (cmb) {
            const int bu = (wq + step) >> 1;
            const float* Ob = MrgO[bu];
#pragma unroll
            for (int s = 0; s < 2; s++) {
                float m1 = MrgML[bu][s][0][lo];
                float l1 = MrgML[bu][s][1][lo];
                float mm = fmaxf(m_i[s], m1);
                float a0 = exp2f(m_i[s] - mm);
                float a1 = exp2f(m1 - mm);
                m_i[s] = mm;
                l_i[s] = l_i[s] * a0 + l1 * a1;
#pragma unroll
                for (int dt = 0; dt < 4; dt++)
#pragma unroll
                    for (int reg = 0; reg < 4; reg++)
                        Oacc[s][dt][reg] = Oacc[s][dt][reg] * a0 +
                                           Ob[(s * 16 + dt * 4 + reg) * 64 + lane] * a1;
            }
        }
    }

    // ---- group leaders (pos==0: waves 0 and na) finalize + store ----
    if (pos == 0) {
#pragma unroll
        for (int s = 0; s < 2; s++) {
            float linv = 1.f / l_i[s];
            bf16_t* Orow = O + ((size_t)(b * SS + q0 + s * 16 + lo)) * DD + h * HD;
#pragma unroll
            for (int dt = 0; dt < 4; dt++) {
                bf16x4 ov;
#pragma unroll
                for (int reg = 0; reg < 4; reg++)
                    ov[reg] = (bf16_t)(Oacc[s][dt][reg] * linv);
                *(bf16x4*)&Orow[dt * 16 + quad * 4] = ov;
            }
        }
    }
}

// ---------------- launch ----------------
extern "C" void kernel_launch(void* const* d_in, const int* in_sizes, int n_in,
                              void* d_out, int out_size, void* d_ws, size_t ws_size,
                              hipStream_t stream) {
    const void* x  = d_in[0];
    const void* Wq = d_in[1];
    const void* Wk = d_in[2];
    const void* Wv = d_in[3];
    const void* Wo = d_in[4];
    // d_in[5] = causal mask — known tril, handled analytically in attn_mfma.

    // Workspace layout:
    // [flag 2xint, 256B] | QA bf16[4096,1024] | Kp bf16[4096,64] |
    // VpT bf16[2][64][2048] | Xb bf16[4096,1024] | Wqb bf16[1024,1024] |
    // Wkb bf16[64,1024] | Wvb bf16[64,1024] | Wob bf16[1024,1024]
    char* ws = (char*)d_ws;
    int* flag = (int*)ws;
    bf16_t* QA  = (bf16_t*)(ws + 256);
    bf16_t* Kp  = QA + (size_t)MM * DD;
    bf16_t* VpT = Kp + (size_t)MM * HD;
    bf16_t* Xb  = VpT + (size_t)BB * HD * SS;
    bf16_t* Wqb = Xb + (size_t)MM * DD;
    bf16_t* Wkb = Wqb + (size_t)DD * DD;
    bf16_t* Wvb = Wkb + (size_t)HD * DD;
    bf16_t* Wob = Wvb + (size_t)HD * DD;
    size_t need = (size_t)((char*)(Wob + (size_t)DD * DD) - ws);

    if (ws_size >= need) {
        // conv_all fuses dtype detection (block-local) and publishes flag
        // for proj_o_b; one fewer serialized launch than detect+conv.
        conv_all<<<dim3(1024), dim3(256), 0, stream>>>(x, Wq, Wk, Wv, Wo,
                                                       Xb, Wqb, Wkb, Wvb, Wob, flag);
        proj_qkv_b<<<dim3(MM / 128, 9), dim3(512), 0, stream>>>(Xb, Wqb, Wkb, Wvb,
                                                                QA, Kp, VpT);
        attn_mfma<<<dim3(32, NH, BB), dim3(512), 0, stream>>>(QA, Kp, VpT, QA);
        proj_o_b<<<dim3(MM / 128, 8), dim3(512), 0, stream>>>(QA, Wob, d_out, flag);
    } else {
        // Fallback: direct-from-input 64x64 path (inline cvt when fp32).
        detect_dtype<<<1, 64, 0, stream>>>((const unsigned int*)x, flag);
        proj_qkv_f<<<dim3(MM / 64, 18), dim3(256), 0, stream>>>(x, Wq, Wk, Wv,
                                                                QA, Kp, VpT, flag);
        attn_mfma<<<dim3(32, NH, BB), dim3(512), 0, stream>>>(QA, Kp, VpT, QA);
        proj_o_f<<<dim3(MM / 64, 16), dim3(256), 0, stream>>>(QA, Wo, d_out,
                                                              flag, flag);
    }
}

// Round 14
// 203.659 us; speedup vs baseline: 1.7991x; 1.0171x over previous
//
#include <hip/hip_runtime.h>
#include <hip/hip_bf16.h>
#include <math.h>

// Problem constants (MultiQueryAttention: B=2, S=2048, D=1024, H=16, hd=64)
#define BB 2
#define SS 2048
#define DD 1024
#define NH 16
#define HD 64
#define MM (BB * SS)  // 4096 tokens

#define BK 64            // GEMM k-step (main path)
#define BKF 32           // fallback k-step

typedef __hip_bfloat16 bf16;
typedef __bf16 bf16_t;
typedef __attribute__((ext_vector_type(8))) __bf16 bf16x8;
typedef __attribute__((ext_vector_type(4))) __bf16 bf16x4;
typedef __attribute__((ext_vector_type(4))) float floatx4;

// (1/sqrt(64)) * log2(e): folded into Q at projection time so QK^T scores
// come out directly in the exp2 domain.
#define SCALEQ 0.18033688011112042f

// bf16-plausibility check for one 32-bit word's low half (as bf16 bits)
__device__ __forceinline__ int bf16_plausible(unsigned int w) {
    unsigned int bits = (w & 0xFFFFu) << 16;
    float v = __uint_as_float(bits);
    float av = fabsf(v);
    return (av == 0.f || (av >= 9.5367431640625e-7f && av <= 64.f)) ? 1 : 0;
}

// ---------------- runtime dtype detection (standalone, fallback path) ----
__global__ void detect_dtype(const unsigned int* __restrict__ x, int* __restrict__ flag) {
    const int tid = threadIdx.x;  // 64 lanes
    int good = 0;
    for (int i = tid; i < 256; i += 64) good += bf16_plausible(x[i]);
#pragma unroll
    for (int s = 1; s < 64; s <<= 1) good += __shfl_xor(good, s);
    if (tid == 0) { flag[0] = (good >= 240) ? 0 : 1; flag[1] = 0; }
}

// ---------------- bulk fp32->bf16 conversion + fused dtype detection -----
__device__ __forceinline__ void conv_seg(const void* __restrict__ in,
                                         bf16_t* __restrict__ out,
                                         int n, int f, int tid, int T) {
    if (f) {
        const float* p = (const float*)in;
        for (int i = tid * 8; i < n; i += T * 8) {
            float4 a = *(const float4*)(p + i);
            float4 b = *(const float4*)(p + i + 4);
            bf16x8 o;
            o[0] = (bf16_t)a.x; o[1] = (bf16_t)a.y; o[2] = (bf16_t)a.z; o[3] = (bf16_t)a.w;
            o[4] = (bf16_t)b.x; o[5] = (bf16_t)b.y; o[6] = (bf16_t)b.z; o[7] = (bf16_t)b.w;
            *(bf16x8*)(out + i) = o;
        }
    } else {
        const bf16_t* p = (const bf16_t*)in;
        for (int i = tid * 8; i < n; i += T * 8)
            *(bf16x8*)(out + i) = *(const bf16x8*)(p + i);
    }
}

__global__ __launch_bounds__(256) void conv_all(const void* __restrict__ x,
                                                const void* __restrict__ wq,
                                                const void* __restrict__ wk,
                                                const void* __restrict__ wv,
                                                const void* __restrict__ wo,
                                                bf16_t* __restrict__ xb,
                                                bf16_t* __restrict__ wqb,
                                                bf16_t* __restrict__ wkb,
                                                bf16_t* __restrict__ wvb,
                                                bf16_t* __restrict__ wob,
                                                int* __restrict__ flag) {
    __shared__ int goodw[4];
    const int ltid = threadIdx.x;
    int g = bf16_plausible(((const unsigned int*)x)[ltid]);
#pragma unroll
    for (int s = 1; s < 64; s <<= 1) g += __shfl_xor(g, s);
    if ((ltid & 63) == 0) goodw[ltid >> 6] = g;
    __syncthreads();
    const int good = goodw[0] + goodw[1] + goodw[2] + goodw[3];
    const int f = (good >= 240) ? 0 : 1;
    if (blockIdx.x == 0 && ltid == 0) { flag[0] = f; flag[1] = 0; }

    const int tid = blockIdx.x * blockDim.x + ltid;
    const int T = gridDim.x * blockDim.x;
    conv_seg(x, xb, MM * DD, f, tid, T);
    conv_seg(wq, wqb, DD * DD, f, tid, T);
    conv_seg(wk, wkb, HD * DD, f, tid, T);
    conv_seg(wv, wvb, HD * DD, f, tid, T);
    conv_seg(wo, wob, DD * DD, f, tid, T);
}

// ------- 128x128-tile bf16 projection GEMMs (512 thr, BK=64, depth-2) ----
// BEST MEASURED CONFIG (R9/R13). Byte-identical to R13.
#define KP2 72

__global__ __launch_bounds__(512) void proj_qkv_b(const bf16_t* __restrict__ X,
                                                  const bf16_t* __restrict__ Wq,
                                                  const bf16_t* __restrict__ Wk,
                                                  const bf16_t* __restrict__ Wv,
                                                  bf16_t* __restrict__ QA,
                                                  bf16_t* __restrict__ Kp,
                                                  bf16_t* __restrict__ VpT) {
    __shared__ bf16_t As[128 * KP2];
    __shared__ bf16_t Bs[128 * KP2];

    const int tid = threadIdx.x;
    const int wave = tid >> 6, lane = tid & 63;
    const int lo = lane & 15, quad = lane >> 4;
    const int wr = wave >> 2, wc = wave & 3;       // 2x4 wave grid
    const int rowBase = blockIdx.x * 128;          // row tile (fastest dim)
    const int cb = blockIdx.y;                     // 0..8 (8 => K|V fused)

    const int rS = tid >> 2;           // 0..127
    const int c16 = (tid & 3) * 16;    // 0,16,32,48

    const bf16_t* arow = X + (size_t)(rowBase + rS) * DD + c16;
    const bf16_t* wrow;
    if (cb < 8)       wrow = Wq + (size_t)(cb * 128 + rS) * DD + c16;
    else if (rS < 64) wrow = Wk + (size_t)rS * DD + c16;
    else              wrow = Wv + (size_t)(rS - 64) * DD + c16;

    floatx4 acc[4][2];
#pragma unroll
    for (int i = 0; i < 4; i++)
#pragma unroll
        for (int j = 0; j < 2; j++) acc[i][j] = (floatx4){0.f, 0.f, 0.f, 0.f};

    bf16x8 aR0[2], bR0[2], aR1[2], bR1[2];
#pragma unroll
    for (int p = 0; p < 2; p++) {
        aR0[p] = *(const bf16x8*)(arow + p * 8);
        bR0[p] = *(const bf16x8*)(wrow + p * 8);
        aR1[p] = *(const bf16x8*)(arow + BK + p * 8);
        bR1[p] = *(const bf16x8*)(wrow + BK + p * 8);
    }

    for (int k0 = 0; k0 < DD; k0 += 2 * BK) {
        __syncthreads();
#pragma unroll
        for (int p = 0; p < 2; p++) {
            *(bf16x8*)&As[rS * KP2 + c16 + p * 8] = aR0[p];
            *(bf16x8*)&Bs[rS * KP2 + c16 + p * 8] = bR0[p];
        }
        __syncthreads();
        if (k0 + 2 * BK < DD) {
#pragma unroll
            for (int p = 0; p < 2; p++) {
                aR0[p] = *(const bf16x8*)(arow + k0 + 2 * BK + p * 8);
                bR0[p] = *(const bf16x8*)(wrow + k0 + 2 * BK + p * 8);
            }
        }
#pragma unroll
        for (int kk = 0; kk < 2; kk++) {
            bf16x8 afr[4], bfr[2];
#pragma unroll
            for (int i = 0; i < 4; i++)
                afr[i] = *(const bf16x8*)&As[(wr * 64 + i * 16 + lo) * KP2 + kk * 32 + quad * 8];
#pragma unroll
            for (int j = 0; j < 2; j++)
                bfr[j] = *(const bf16x8*)&Bs[(wc * 32 + j * 16 + lo) * KP2 + kk * 32 + quad * 8];
#pragma unroll
            for (int i = 0; i < 4; i++)
#pragma unroll
                for (int j = 0; j < 2; j++)
                    acc[i][j] = __builtin_amdgcn_mfma_f32_16x16x32_bf16(afr[i], bfr[j], acc[i][j], 0, 0, 0);
        }
        __syncthreads();
#pragma unroll
        for (int p = 0; p < 2; p++) {
            *(bf16x8*)&As[rS * KP2 + c16 + p * 8] = aR1[p];
            *(bf16x8*)&Bs[rS * KP2 + c16 + p * 8] = bR1[p];
        }
        __syncthreads();
        if (k0 + 3 * BK < DD) {
#pragma unroll
            for (int p = 0; p < 2; p++) {
                aR1[p] = *(const bf16x8*)(arow + k0 + 3 * BK + p * 8);
                bR1[p] = *(const bf16x8*)(wrow + k0 + 3 * BK + p * 8);
            }
        }
#pragma unroll
        for (int kk = 0; kk < 2; kk++) {
            bf16x8 afr[4], bfr[2];
#pragma unroll
            for (int i = 0; i < 4; i++)
                afr[i] = *(const bf16x8*)&As[(wr * 64 + i * 16 + lo) * KP2 + kk * 32 + quad * 8];
#pragma unroll
            for (int j = 0; j < 2; j++)
                bfr[j] = *(const bf16x8*)&Bs[(wc * 32 + j * 16 + lo) * KP2 + kk * 32 + quad * 8];
#pragma unroll
            for (int i = 0; i < 4; i++)
#pragma unroll
                for (int j = 0; j < 2; j++)
                    acc[i][j] = __builtin_amdgcn_mfma_f32_16x16x32_bf16(afr[i], bfr[j], acc[i][j], 0, 0, 0);
        }
    }

#pragma unroll
    for (int i = 0; i < 4; i++)
#pragma unroll
        for (int j = 0; j < 2; j++)
#pragma unroll
            for (int reg = 0; reg < 4; reg++) {
                int row = rowBase + wr * 64 + i * 16 + quad * 4 + reg;  // token
                int c = wc * 32 + j * 16 + lo;                          // 0..127
                float v = acc[i][j][reg];
                if (cb < 8) {
                    QA[(size_t)row * DD + cb * 128 + c] = (bf16_t)(v * SCALEQ);
                } else if (c < 64) {
                    Kp[(size_t)row * HD + c] = (bf16_t)v;
                } else {
                    VpT[((size_t)(row >> 11) * HD + (c - 64)) * SS + (row & (SS - 1))] = (bf16_t)v;
                }
            }
}

__global__ __launch_bounds__(512) void proj_o_b(const bf16_t* __restrict__ AO,
                                                const bf16_t* __restrict__ Wo,
                                                void* __restrict__ Cout,
                                                const int* __restrict__ flagOut) {
    const int fout = *flagOut;

    __shared__ bf16_t As[128 * KP2];
    __shared__ bf16_t Bs[128 * KP2];

    const int tid = threadIdx.x;
    const int wave = tid >> 6, lane = tid & 63;
    const int lo = lane & 15, quad = lane >> 4;
    const int wr = wave >> 2, wc = wave & 3;
    const int rowBase = blockIdx.x * 128;          // row tile (fastest dim)
    const int colBase = blockIdx.y * 128;

    const int rS = tid >> 2;
    const int c16 = (tid & 3) * 16;

    const bf16_t* arow = AO + (size_t)(rowBase + rS) * DD + c16;
    const bf16_t* wrow = Wo + (size_t)(colBase + rS) * DD + c16;

    floatx4 acc[4][2];
#pragma unroll
    for (int i = 0; i < 4; i++)
#pragma unroll
        for (int j = 0; j < 2; j++) acc[i][j] = (floatx4){0.f, 0.f, 0.f, 0.f};

    bf16x8 aR0[2], bR0[2], aR1[2], bR1[2];
#pragma unroll
    for (int p = 0; p < 2; p++) {
        aR0[p] = *(const bf16x8*)(arow + p * 8);
        bR0[p] = *(const bf16x8*)(wrow + p * 8);
        aR1[p] = *(const bf16x8*)(arow + BK + p * 8);
        bR1[p] = *(const bf16x8*)(wrow + BK + p * 8);
    }

    for (int k0 = 0; k0 < DD; k0 += 2 * BK) {
        __syncthreads();
#pragma unroll
        for (int p = 0; p < 2; p++) {
            *(bf16x8*)&As[rS * KP2 + c16 + p * 8] = aR0[p];
            *(bf16x8*)&Bs[rS * KP2 + c16 + p * 8] = bR0[p];
        }
        __syncthreads();
        if (k0 + 2 * BK < DD) {
#pragma unroll
            for (int p = 0; p < 2; p++) {
                aR0[p] = *(const bf16x8*)(arow + k0 + 2 * BK + p * 8);
                bR0[p] = *(const bf16x8*)(wrow + k0 + 2 * BK + p * 8);
            }
        }
#pragma unroll
        for (int kk = 0; kk < 2; kk++) {
            bf16x8 afr[4], bfr[2];
#pragma unroll
            for (int i = 0; i < 4; i++)
                afr[i] = *(const bf16x8*)&As[(wr * 64 + i * 16 + lo) * KP2 + kk * 32 + quad * 8];
#pragma unroll
            for (int j = 0; j < 2; j++)
                bfr[j] = *(const bf16x8*)&Bs[(wc * 32 + j * 16 + lo) * KP2 + kk * 32 + quad * 8];
#pragma unroll
            for (int i = 0; i < 4; i++)
#pragma unroll
                for (int j = 0; j < 2; j++)
                    acc[i][j] = __builtin_amdgcn_mfma_f32_16x16x32_bf16(afr[i], bfr[j], acc[i][j], 0, 0, 0);
        }
        __syncthreads();
#pragma unroll
        for (int p = 0; p < 2; p++) {
            *(bf16x8*)&As[rS * KP2 + c16 + p * 8] = aR1[p];
            *(bf16x8*)&Bs[rS * KP2 + c16 + p * 8] = bR1[p];
        }
        __syncthreads();
        if (k0 + 3 * BK < DD) {
#pragma unroll
            for (int p = 0; p < 2; p++) {
                aR1[p] = *(const bf16x8*)(arow + k0 + 3 * BK + p * 8);
                bR1[p] = *(const bf16x8*)(wrow + k0 + 3 * BK + p * 8);
            }
        }
#pragma unroll
        for (int kk = 0; kk < 2; kk++) {
            bf16x8 afr[4], bfr[2];
#pragma unroll
            for (int i = 0; i < 4; i++)
                afr[i] = *(const bf16x8*)&As[(wr * 64 + i * 16 + lo) * KP2 + kk * 32 + quad * 8];
#pragma unroll
            for (int j = 0; j < 2; j++)
                bfr[j] = *(const bf16x8*)&Bs[(wc * 32 + j * 16 + lo) * KP2 + kk * 32 + quad * 8];
#pragma unroll
            for (int i = 0; i < 4; i++)
#pragma unroll
                for (int j = 0; j < 2; j++)
                    acc[i][j] = __builtin_amdgcn_mfma_f32_16x16x32_bf16(afr[i], bfr[j], acc[i][j], 0, 0, 0);
        }
    }

#pragma unroll
    for (int i = 0; i < 4; i++)
#pragma unroll
        for (int j = 0; j < 2; j++)
#pragma unroll
            for (int reg = 0; reg < 4; reg++) {
                int row = rowBase + wr * 64 + i * 16 + quad * 4 + reg;
                int col = colBase + wc * 32 + j * 16 + lo;
                size_t idx = (size_t)row * DD + col;
                if (fout) ((float*)Cout)[idx] = acc[i][j][reg];
                else      ((bf16_t*)Cout)[idx] = (bf16_t)acc[i][j][reg];
            }
}

// -------- fallback projections (direct input, ws too small) --------------
#define KP 40

__device__ __forceinline__ bf16x8 ld8(const void* p, int f, size_t idx) {
    if (f) {
        const float* q = (const float*)p + idx;
        float4 a = *(const float4*)(q);
        float4 b = *(const float4*)(q + 4);
        bf16x8 o;
        o[0] = (bf16_t)a.x; o[1] = (bf16_t)a.y; o[2] = (bf16_t)a.z; o[3] = (bf16_t)a.w;
        o[4] = (bf16_t)b.x; o[5] = (bf16_t)b.y; o[6] = (bf16_t)b.z; o[7] = (bf16_t)b.w;
        return o;
    }
    return *(const bf16x8*)((const bf16_t*)p + idx);
}

__global__ __launch_bounds__(256) void proj_qkv_f(const void* __restrict__ X,
                                                  const void* __restrict__ Wq,
                                                  const void* __restrict__ Wk,
                                                  const void* __restrict__ Wv,
                                                  bf16_t* __restrict__ QA,
                                                  bf16_t* __restrict__ Kp,
                                                  bf16_t* __restrict__ VpT,
                                                  const int* __restrict__ flag) {
    const int f = *flag;
    __shared__ bf16_t As[64 * KP];
    __shared__ bf16_t Bs[64 * KP];

    const int tid = threadIdx.x;
    const int wave = tid >> 6, lane = tid & 63;
    const int lo = lane & 15, quad = lane >> 4;
    const int wr = wave >> 1, wc = wave & 1;
    const int rowBase = blockIdx.x * 64;
    const int cb = blockIdx.y;

    const int rS = tid >> 2;
    const int c8 = (tid & 3) * 8;

    size_t aidx = (size_t)(rowBase + rS) * DD + c8;
    size_t widx;
    const void* Wsrc;
    if (cb < 16)       { Wsrc = Wq; widx = (size_t)(cb * 64 + rS) * DD + c8; }
    else if (cb == 16) { Wsrc = Wk; widx = (size_t)rS * DD + c8; }
    else               { Wsrc = Wv; widx = (size_t)rS * DD + c8; }

    floatx4 acc[2][2];
#pragma unroll
    for (int i = 0; i < 2; i++)
#pragma unroll
        for (int j = 0; j < 2; j++) acc[i][j] = (floatx4){0.f, 0.f, 0.f, 0.f};

    for (int k0 = 0; k0 < DD; k0 += BKF) {
        __syncthreads();
        *(bf16x8*)&As[rS * KP + c8] = ld8(X, f, aidx + k0);
        *(bf16x8*)&Bs[rS * KP + c8] = ld8(Wsrc, f, widx + k0);
        __syncthreads();
        bf16x8 afr[2], bfr[2];
#pragma unroll
        for (int i = 0; i < 2; i++)
            afr[i] = *(const bf16x8*)&As[(wr * 32 + i * 16 + lo) * KP + quad * 8];
#pragma unroll
        for (int j = 0; j < 2; j++)
            bfr[j] = *(const bf16x8*)&Bs[(wc * 32 + j * 16 + lo) * KP + quad * 8];
#pragma unroll
        for (int i = 0; i < 2; i++)
#pragma unroll
            for (int j = 0; j < 2; j++)
                acc[i][j] = __builtin_amdgcn_mfma_f32_16x16x32_bf16(afr[i], bfr[j], acc[i][j], 0, 0, 0);
    }

#pragma unroll
    for (int i = 0; i < 2; i++)
#pragma unroll
        for (int j = 0; j < 2; j++)
#pragma unroll
            for (int reg = 0; reg < 4; reg++) {
                int row = rowBase + wr * 32 + i * 16 + quad * 4 + reg;
                int c = wc * 32 + j * 16 + lo;
                float v = acc[i][j][reg];
                if (cb < 16) {
                    QA[(size_t)row * DD + cb * 64 + c] = (bf16_t)(v * SCALEQ);
                } else if (cb == 16) {
                    Kp[(size_t)row * HD + c] = (bf16_t)v;
                } else {
                    VpT[((size_t)(row >> 11) * HD + c) * SS + (row & (SS - 1))] = (bf16_t)v;
                }
            }
}

__global__ __launch_bounds__(256) void proj_o_f(const bf16_t* __restrict__ AO,
                                                const void* __restrict__ Wo,
                                                void* __restrict__ Cout,
                                                const int* __restrict__ flagW,
                                                const int* __restrict__ flagOut) {
    const int f = *flagW;
    const int fout = *flagOut;
    __shared__ bf16_t As[64 * KP];
    __shared__ bf16_t Bs[64 * KP];

    const int tid = threadIdx.x;
    const int wave = tid >> 6, lane = tid & 63;
    const int lo = lane & 15, quad = lane >> 4;
    const int wr = wave >> 1, wc = wave & 1;
    const int rowBase = blockIdx.x * 64;
    const int colBase = blockIdx.y * 64;

    const int rS = tid >> 2;
    const int c8 = (tid & 3) * 8;

    size_t aidx = (size_t)(rowBase + rS) * DD + c8;
    size_t widx = (size_t)(colBase + rS) * DD + c8;

    floatx4 acc[2][2];
#pragma unroll
    for (int i = 0; i < 2; i++)
#pragma unroll
        for (int j = 0; j < 2; j++) acc[i][j] = (floatx4){0.f, 0.f, 0.f, 0.f};

    for (int k0 = 0; k0 < DD; k0 += BKF) {
        __syncthreads();
        *(bf16x8*)&As[rS * KP + c8] = *(const bf16x8*)(AO + aidx + k0);
        *(bf16x8*)&Bs[rS * KP + c8] = ld8(Wo, f, widx + k0);
        __syncthreads();
        bf16x8 afr[2], bfr[2];
#pragma unroll
        for (int i = 0; i < 2; i++)
            afr[i] = *(const bf16x8*)&As[(wr * 32 + i * 16 + lo) * KP + quad * 8];
#pragma unroll
        for (int j = 0; j < 2; j++)
            bfr[j] = *(const bf16x8*)&Bs[(wc * 32 + j * 16 + lo) * KP + quad * 8];
#pragma unroll
        for (int i = 0; i < 2; i++)
#pragma unroll
            for (int j = 0; j < 2; j++)
                acc[i][j] = __builtin_amdgcn_mfma_f32_16x16x32_bf16(afr[i], bfr[j], acc[i][j], 0, 0, 0);
    }

#pragma unroll
    for (int i = 0; i < 2; i++)
#pragma unroll
        for (int j = 0; j < 2; j++)
#pragma unroll
            for (int reg = 0; reg < 4; reg++) {
                int row = rowBase + wr * 32 + i * 16 + quad * 4 + reg;
                int col = colBase + wc * 32 + j * 16 + lo;
                size_t idx = (size_t)row * DD + col;
                if (fout) ((float*)Cout)[idx] = acc[i][j][reg];
                else      ((bf16_t*)Cout)[idx] = (bf16_t)acc[i][j][reg];
            }
}

// -------- MFMA flash attention, balanced key-split, KVBLK=64 -------------
// 512-thread blocks (8 waves), pair (x, 63-x): 33 64-key blocks per pair
// by construction (exact for all x). Per 64-block, the fixed serial costs
// (loop bookkeeping, trigger+branch, lgkmcnt sync, P round-trip) are paid
// ONCE for 2x the MFMA/exp2 work -> better amortization + ILP. Register
// plan keeps peak live ~110 < 128: K loaded per 32-half with register
// reuse (no cross-block prefetch; its latency amortizes over doubled
// compute), st[2][4] lives only while kf is dead. __launch_bounds__(512,4):
// full 128-reg bin. PROVEN: caps 64/85/102 all spill catastrophically.
#define PSTR2 72
#define DMTHR 8.0f    // defer-max threshold (exp2 domain)

__global__ __launch_bounds__(512, 4) void attn_mfma(const bf16_t* Q,
                                                    const bf16_t* __restrict__ K,
                                                    const bf16_t* __restrict__ Vt,
                                                    bf16_t* O) {
    const int h = blockIdx.y, b = blockIdx.z;
    const int tid = threadIdx.x;
    const int wq = tid >> 6, lane = tid & 63;
    const int lo = lane & 15, quad = lane >> 4;
    const int x = blockIdx.x;           // 0..31 -> pair (x, 63-x)

    // --- proportional wave->q-tile assignment over 64-key blocks ---
    const int nA = (x + 2) >> 1;        // 64-blocks for qt=x (pair total 33)
    int na = 1, bestc = 0x7fffffff;
#pragma unroll
    for (int a = 1; a <= 7; ++a) {
        int cA = (nA + a - 1) / a;
        int cB = (33 - nA + (7 - a)) / (8 - a);
        int c = cA > cB ? cA : cB;
        if (c < bestc) { bestc = c; na = a; }
    }
    int qt, pos, gs;
    if (wq < na) { qt = x;      pos = wq;      gs = na; }
    else         { qt = 63 - x; pos = wq - na; gs = 8 - na; }
    const int q0 = qt * 32;
    const int n64 = (qt + 2) >> 1;      // 64-key blocks for this q-tile
    const int itS = (n64 * pos) / gs;
    const int itE = (n64 * (pos + 1)) / gs;

    // --- LDS: P staging (per-wave, 32 x 64 + pad) unions merge buffers ---
    __shared__ __align__(16) char smem[8 * 32 * PSTR2 * 2];  // 36864 B
    __shared__ float MrgML[4][2][2][16];                     // [buf][s][m/l][lo]
    bf16_t* Pw = (bf16_t*)smem + wq * (32 * PSTR2);          // 4608 B/wave
    float (*MrgO)[32 * 64] = (float (*)[32 * 64])smem;       // 4 bufs x 8 KB

    // Q frags (B operand: n=q, k=dim); Q already scaled by (1/8)*log2(e)
    bf16x8 qf[2][2];
#pragma unroll
    for (int s = 0; s < 2; s++)
#pragma unroll
        for (int hf = 0; hf < 2; hf++)
            qf[s][hf] = *(const bf16x8*)(Q + ((size_t)(b * SS + q0 + s * 16 + lo)) * DD +
                                         h * HD + hf * 32 + quad * 8);

    floatx4 Oacc[2][4];
    float m_i[2], l_ln[2];   // m: column-consistent running max; l: LANE-partial
#pragma unroll
    for (int s = 0; s < 2; s++) {
#pragma unroll
        for (int dt = 0; dt < 4; dt++) Oacc[s][dt] = (floatx4){0.f, 0.f, 0.f, 0.f};
        m_i[s] = -1e30f; l_ln[s] = 0.f;
    }

    const bf16_t* Kb = K + (size_t)b * SS * HD;
    const bf16_t* Vb = Vt + (size_t)b * HD * SS;

    for (int it = itS; it < itE; it++) {
        const int t0 = it * 64;

        // S^T = K.Q^T for 64 keys: two 32-halves, kf registers reused
        floatx4 st[2][4];
        {
            bf16x8 kf[2][2];
#pragma unroll
            for (int kt = 0; kt < 2; kt++)
#pragma unroll
                for (int hf = 0; hf < 2; hf++)
                    kf[kt][hf] = *(const bf16x8*)(Kb + (size_t)(t0 + kt * 16 + lo) * HD +
                                                  hf * 32 + quad * 8);
#pragma unroll
            for (int s = 0; s < 2; s++)
#pragma unroll
                for (int kt = 0; kt < 2; kt++) {
                    floatx4 z = (floatx4){0.f, 0.f, 0.f, 0.f};
                    z = __builtin_amdgcn_mfma_f32_16x16x32_bf16(kf[kt][0], qf[s][0], z, 0, 0, 0);
                    z = __builtin_amdgcn_mfma_f32_16x16x32_bf16(kf[kt][1], qf[s][1], z, 0, 0, 0);
                    st[s][kt] = z;
                }
#pragma unroll
            for (int kt = 0; kt < 2; kt++)
#pragma unroll
                for (int hf = 0; hf < 2; hf++)
                    kf[kt][hf] = *(const bf16x8*)(Kb + (size_t)(t0 + 32 + kt * 16 + lo) * HD +
                                                  hf * 32 + quad * 8);
#pragma unroll
            for (int s = 0; s < 2; s++)
#pragma unroll
                for (int kt = 0; kt < 2; kt++) {
                    floatx4 z = (floatx4){0.f, 0.f, 0.f, 0.f};
                    z = __builtin_amdgcn_mfma_f32_16x16x32_bf16(kf[kt][0], qf[s][0], z, 0, 0, 0);
                    z = __builtin_amdgcn_mfma_f32_16x16x32_bf16(kf[kt][1], qf[s][1], z, 0, 0, 0);
                    st[s][2 + kt] = z;
                }
        }

        // diagonal block (always the last block of this q-tile): mask k > q.
        // Covers both the causal boundary and (qt even) the padded half.
        if ((qt >> 1) == it) {
#pragma unroll
            for (int s = 0; s < 2; s++) {
                int q = q0 + s * 16 + lo;
#pragma unroll
                for (int kt = 0; kt < 4; kt++)
#pragma unroll
                    for (int reg = 0; reg < 4; reg++)
                        if (t0 + kt * 16 + quad * 4 + reg > q) st[s][kt][reg] = -1e30f;
            }
        }

        // defer-max online softmax over 64 keys (shuffle-free common case)
#pragma unroll
        for (int s = 0; s < 2; s++) {
            float lm = fmaxf(
                fmaxf(fmaxf(fmaxf(st[s][0][0], st[s][0][1]), fmaxf(st[s][0][2], st[s][0][3])),
                      fmaxf(fmaxf(st[s][1][0], st[s][1][1]), fmaxf(st[s][1][2], st[s][1][3]))),
                fmaxf(fmaxf(fmaxf(st[s][2][0], st[s][2][1]), fmaxf(st[s][2][2], st[s][2][3])),
                      fmaxf(fmaxf(st[s][3][0], st[s][3][1]), fmaxf(st[s][3][2], st[s][3][3]))));
            if (__any(lm > m_i[s] + DMTHR)) {
                float mx = fmaxf(lm, __shfl_xor(lm, 16));
                mx = fmaxf(mx, __shfl_xor(mx, 32));
                float mn = fmaxf(m_i[s], mx);
                float al = exp2f(m_i[s] - mn);
                m_i[s] = mn;
                l_ln[s] *= al;
#pragma unroll
                for (int dt = 0; dt < 4; dt++) Oacc[s][dt] *= al;
            }
            float rs = 0.f;
#pragma unroll
            for (int kt = 0; kt < 4; kt++) {
#pragma unroll
                for (int reg = 0; reg < 4; reg++)
                    st[s][kt][reg] = exp2f(st[s][kt][reg] - m_i[s]);
                rs += (st[s][kt][0] + st[s][kt][1]) + (st[s][kt][2] + st[s][kt][3]);
            }
            l_ln[s] += rs;
#pragma unroll
            for (int kt = 0; kt < 4; kt++) {
                bf16x4 pk;
#pragma unroll
                for (int reg = 0; reg < 4; reg++) pk[reg] = (bf16_t)st[s][kt][reg];
                *(bf16x4*)&Pw[(s * 16 + lo) * PSTR2 + kt * 16 + quad * 4] = pk;
            }
        }

        asm volatile("s_waitcnt lgkmcnt(0)" ::: "memory");

        // O^T += V^T . P^T, per 32-half (vf registers reused)
#pragma unroll
        for (int hb = 0; hb < 2; hb++) {
            bf16x8 vf[4];
#pragma unroll
            for (int dt = 0; dt < 4; dt++)
                vf[dt] = *(const bf16x8*)(Vb + (size_t)(dt * 16 + lo) * SS +
                                          t0 + hb * 32 + quad * 8);
            bf16x8 pb[2];
#pragma unroll
            for (int s = 0; s < 2; s++)
                pb[s] = *(const bf16x8*)&Pw[(s * 16 + lo) * PSTR2 + hb * 32 + quad * 8];
#pragma unroll
            for (int s = 0; s < 2; s++)
#pragma unroll
                for (int dt = 0; dt < 4; dt++)
                    Oacc[s][dt] = __builtin_amdgcn_mfma_f32_16x16x32_bf16(vf[dt], pb[s], Oacc[s][dt], 0, 0, 0);
        }
    }

    // ---- finalize lane-partial l into column-consistent l_i ----
    float l_i[2];
#pragma unroll
    for (int s = 0; s < 2; s++) {
        float l = l_ln[s];
        l += __shfl_xor(l, 16);
        l += __shfl_xor(l, 32);
        l_i[s] = l;
    }

    // ---- binary-tree merge within each wave group (flash merge algebra) ----
    for (int step = 1; step < 8; step <<= 1) {
        const bool pub = (pos & (2 * step - 1)) == step;
        const bool cmb = ((pos & (2 * step - 1)) == 0) && (pos + step < gs);
        __syncthreads();   // previous round's reads (and P-staging use) done
        if (pub) {
            float* Ob = MrgO[wq >> 1];
#pragma unroll
            for (int s = 0; s < 2; s++) {
#pragma unroll
                for (int dt = 0; dt < 4; dt++)
#pragma unroll
                    for (int reg = 0; reg < 4; reg++)
                        Ob[(s * 16 + dt * 4 + reg) * 64 + lane] = Oacc[s][dt][reg];
                if (quad == 0) {
                    MrgML[wq >> 1][s][0][lo] = m_i[s];
                    MrgML[wq >> 1][s][1][lo] = l_i[s];
                }
            }
        }
        __syncthreads();
        if (cmb) {
            const int bu = (wq + step) >> 1;
            const float* Ob = MrgO[bu];
#pragma unroll
            for (int s = 0; s < 2; s++) {
                float m1 = MrgML[bu][s][0][lo];
                float l1 = MrgML[bu][s][1][lo];
                float mm = fmaxf(m_i[s], m1);
                float a0 = exp2f(m_i[s] - mm);
                float a1 = exp2f(m1 - mm);
                m_i[s] = mm;
                l_i[s] = l_i[s] * a0 + l1 * a1;
#pragma unroll
                for (int dt = 0; dt < 4; dt++)
#pragma unroll
                    for (int reg = 0; reg < 4; reg++)
                        Oacc[s][dt][reg] = Oacc[s][dt][reg] * a0 +
                                           Ob[(s * 16 + dt * 4 + reg) * 64 + lane] * a1;
            }
        }
    }

    // ---- group leaders (pos==0: waves 0 and na) finalize + store ----
    if (pos == 0) {
#pragma unroll
        for (int s = 0; s < 2; s++) {
            float linv = 1.f / l_i[s];
            bf16_t* Orow = O + ((size_t)(b * SS + q0 + s * 16 + lo)) * DD + h * HD;
#pragma unroll
            for (int dt = 0; dt < 4; dt++) {
                bf16x4 ov;
#pragma unroll
                for (int reg = 0; reg < 4; reg++)
                    ov[reg] = (bf16_t)(Oacc[s][dt][reg] * linv);
                *(bf16x4*)&Orow[dt * 16 + quad * 4] = ov;
            }
        }
    }
}

// ---------------- launch ----------------
extern "C" void kernel_launch(void* const* d_in, const int* in_sizes, int n_in,
                              void* d_out, int out_size, void* d_ws, size_t ws_size,
                              hipStream_t stream) {
    const void* x  = d_in[0];
    const void* Wq = d_in[1];
    const void* Wk = d_in[2];
    const void* Wv = d_in[3];
    const void* Wo = d_in[4];
    // d_in[5] = causal mask — known tril, handled analytically in attn_mfma.

    // Workspace layout:
    // [flag 2xint, 256B] | QA bf16[4096,1024] | Kp bf16[4096,64] |
    // VpT bf16[2][64][2048] | Xb bf16[4096,1024] | Wqb bf16[1024,1024] |
    // Wkb bf16[64,1024] | Wvb bf16[64,1024] | Wob bf16[1024,1024]
    char* ws = (char*)d_ws;
    int* flag = (int*)ws;
    bf16_t* QA  = (bf16_t*)(ws + 256);
    bf16_t* Kp  = QA + (size_t)MM * DD;
    bf16_t* VpT = Kp + (size_t)MM * HD;
    bf16_t* Xb  = VpT + (size_t)BB * HD * SS;
    bf16_t* Wqb = Xb + (size_t)MM * DD;
    bf16_t* Wkb = Wqb + (size_t)DD * DD;
    bf16_t* Wvb = Wkb + (size_t)HD * DD;
    bf16_t* Wob = Wvb + (size_t)HD * DD;
    size_t need = (size_t)((char*)(Wob + (size_t)DD * DD) - ws);

    if (ws_size >= need) {
        // conv_all fuses dtype detection (block-local) and publishes flag
        // for proj_o_b; one fewer serialized launch than detect+conv.
        conv_all<<<dim3(1024), dim3(256), 0, stream>>>(x, Wq, Wk, Wv, Wo,
                                                       Xb, Wqb, Wkb, Wvb, Wob, flag);
        proj_qkv_b<<<dim3(MM / 128, 9), dim3(512), 0, stream>>>(Xb, Wqb, Wkb, Wvb,
                                                                QA, Kp, VpT);
        attn_mfma<<<dim3(32, NH, BB), dim3(512), 0, stream>>>(QA, Kp, VpT, QA);
        proj_o_b<<<dim3(MM / 128, 8), dim3(512), 0, stream>>>(QA, Wob, d_out, flag);
    } else {
        // Fallback: direct-from-input 64x64 path (inline cvt when fp32).
        detect_dtype<<<1, 64, 0, stream>>>((const unsigned int*)x, flag);
        proj_qkv_f<<<dim3(MM / 64, 18), dim3(256), 0, stream>>>(x, Wq, Wk, Wv,
                                                                QA, Kp, VpT, flag);
        attn_mfma<<<dim3(32, NH, BB), dim3(512), 0, stream>>>(QA, Kp, VpT, QA);
        proj_o_f<<<dim3(MM / 64, 16), dim3(256), 0, stream>>>(QA, Wo, d_out,
                                                              flag, flag);
    }
}